// Round 1
// baseline (1140.341 us; speedup 1.0000x reference)
//
#include <hip/hip_runtime.h>
#include <hip/hip_bf16.h>

typedef __attribute__((ext_vector_type(8))) short short8;
typedef __attribute__((ext_vector_type(4))) float f32x4;
using bf16_t = __hip_bfloat16;
using bf162_t = __hip_bfloat162;

#define FD 512

__device__ __forceinline__ float ldf(const void* p, size_t i, int f32) {
  return f32 ? ((const float*)p)[i] : __bfloat162float(((const bf16_t*)p)[i]);
}

// CK-pattern async global->LDS, 16B per lane (global_load_lds_dwordx4)
__device__ __forceinline__ void glds16(const bf16_t* g, short* l) {
  __builtin_amdgcn_global_load_lds(
      (const __attribute__((address_space(1))) unsigned int*)g,
      (__attribute__((address_space(3))) unsigned int*)(uintptr_t)l, 16, 0, 0);
}

// ---------------- dtype detect (fp32 vs bf16 device tensors) ----------------
__global__ void detect_k(const unsigned int* w, int nwords, int* flag) {
  __shared__ int cnt_s;
  if (threadIdx.x == 0) cnt_s = 0;
  __syncthreads();
  int c = 0;
  for (int i = threadIdx.x; i < nwords; i += 256) {
    unsigned lo = w[i] & 0xFFFFu;
    unsigned ex = (lo >> 7) & 0xFFu;
    if (lo == 0u || (ex >= 100u && ex <= 140u)) c++;
  }
  atomicAdd(&cnt_s, c);
  __syncthreads();
  if (threadIdx.x == 0) *flag = (2 * cnt_s < nwords) ? 1 : 0;
}

// convert h (z=0: disease, z=1: protein) to canonical bf16, zero pad rows
__global__ void conv_h_k(const void* s0, const void* s1, bf16_t* d0, bf16_t* d1, int n, int npad,
                         const int* flag) {
  int f = *flag;
  const void* src = blockIdx.y ? s1 : s0;
  bf16_t* dst = blockIdx.y ? d1 : d0;
  int e = (blockIdx.x * 256 + threadIdx.x) * 4;
  if (e >= npad) return;
  bf162_t o0, o1;
  if (e + 3 < n) {
    o0.x = __float2bfloat16(ldf(src, e + 0, f));
    o0.y = __float2bfloat16(ldf(src, e + 1, f));
    o1.x = __float2bfloat16(ldf(src, e + 2, f));
    o1.y = __float2bfloat16(ldf(src, e + 3, f));
  } else {
    float v[4];
    for (int u = 0; u < 4; ++u) v[u] = (e + u < n) ? ldf(src, e + u, f) : 0.f;
    o0.x = __float2bfloat16(v[0]); o0.y = __float2bfloat16(v[1]);
    o1.x = __float2bfloat16(v[2]); o1.y = __float2bfloat16(v[3]);
  }
  *(bf162_t*)(dst + e) = o0;
  *(bf162_t*)(dst + e + 2) = o1;
}

// ---------------- CSR build ----------------
__global__ void count_deg_k(const int* __restrict__ a_src, const int* __restrict__ a_dst,
                            const int* __restrict__ i_src, const int* __restrict__ i_dst,
                            int* __restrict__ deg, int M, int E) {
  int e = blockIdx.x * 256 + threadIdx.x;
  if (e >= E) return;
  atomicAdd(&deg[0 * M + a_dst[e]], 1);
  atomicAdd(&deg[1 * M + a_src[e]], 1);
  atomicAdd(&deg[2 * M + i_dst[e]], 1);
  atomicAdd(&deg[3 * M + i_src[e]], 1);
}

__global__ void scan_k(const int* __restrict__ deg, int* __restrict__ offs,
                       int* __restrict__ curs, int n) {
  const int r = blockIdx.x;
  const int* d = deg + r * n;
  int* off = offs + r * (n + 1);
  int* cur = curs + r * n;
  __shared__ int part[256];
  const int t = threadIdx.x;
  const int chunk = (n + 255) / 256;
  const int s0 = t * chunk;
  const int s1 = min(n, s0 + chunk);
  int sum = 0;
  for (int i = s0; i < s1; ++i) sum += d[i];
  part[t] = sum;
  __syncthreads();
  if (t == 0) {
    int run = 0;
    for (int i = 0; i < 256; ++i) { int v = part[i]; part[i] = run; run += v; }
  }
  __syncthreads();
  int run = part[t];
  for (int i = s0; i < s1; ++i) { off[i] = run; cur[i] = run; run += d[i]; }
  if (t == 255) off[n] = run;
}

__global__ void fill_k(const int* __restrict__ a_src, const int* __restrict__ a_dst,
                       const int* __restrict__ i_src, const int* __restrict__ i_dst,
                       int* __restrict__ curs, int* __restrict__ evals, int M, int E) {
  int r = blockIdx.y;
  int e = blockIdx.x * 256 + threadIdx.x;
  if (e >= E) return;
  const int* dsts[4] = {a_dst, a_src, i_dst, i_src};
  const int* vals[4] = {a_src, a_dst, i_src, i_dst};
  int d = dsts[r][e];
  int pos = atomicAdd(&curs[r * M + d], 1);
  evals[r * E + pos] = vals[r][e];
}

// ---------------- feature-sliced fused segment mean ----------------
// 8 slices of 64 feats: a (table, slice) working set is 20000*64*2B = 2.56 MB
// -> fully L2-resident per XCD during its pass. blockIdx.y = pass id:
//   y in [0,24): rel = 1 + y%3 (all gather h_p), slice = y/3  -> 3 rels share slice
//   y in [24,32): rel = 0 (gathers h_d), slice = y-24
// Each half-wave (32 lanes x 4B = 128B row-slice) owns one node completely:
// no LDS reduction, no bank conflicts, coalesced 128B output stores.
__device__ __forceinline__ void upacc(unsigned u, float& a0, float& a1) {
  bf162_t b = *(bf162_t*)&u;
  a0 += __bfloat162float(b.x);
  a1 += __bfloat162float(b.y);
}

__global__ void seg_mean_sl_k(const bf16_t* __restrict__ hd, const bf16_t* __restrict__ hp,
                              const int* __restrict__ offs, const int* __restrict__ evals,
                              int Mn, int E,
                              bf16_t* __restrict__ m0b, bf16_t* __restrict__ m1b,
                              bf16_t* __restrict__ m2b, bf16_t* __restrict__ m3b) {
  const int y = blockIdx.y;
  int rel, sl;
  if (y < 24) { rel = 1 + y % 3; sl = y / 3; }
  else        { rel = 0;         sl = y - 24; }
  const bf16_t* __restrict__ h = (rel == 0) ? hd : hp;
  bf16_t* mb = (rel == 0) ? m0b : (rel == 1) ? m1b : (rel == 2) ? m2b : m3b;

  const int t = threadIdx.x;
  const int hw = t >> 5, sub = t & 31;
  const int node = blockIdx.x * 8 + hw;  // grid.x = Mp/8; pad nodes write zeros
  int s = 0, e = 0;
  if (node < Mn) {
    const int* off = offs + rel * (Mn + 1) + node;
    s = off[0];
    e = off[1];
  }
  const int* __restrict__ ev = evals + (size_t)rel * E;
  const bf16_t* hs = h + sl * 64 + sub * 2;

  float a0 = 0.f, a1 = 0.f;
  int c = s;
  for (; c + 3 < e; c += 4) {  // 4 independent 4B loads in flight per lane
    int n0 = ev[c], n1 = ev[c + 1], n2 = ev[c + 2], n3 = ev[c + 3];
    unsigned u0 = *(const unsigned*)(hs + n0 * FD);
    unsigned u1 = *(const unsigned*)(hs + n1 * FD);
    unsigned u2 = *(const unsigned*)(hs + n2 * FD);
    unsigned u3 = *(const unsigned*)(hs + n3 * FD);
    upacc(u0, a0, a1);
    upacc(u1, a0, a1);
    upacc(u2, a0, a1);
    upacc(u3, a0, a1);
  }
  for (; c < e; ++c) {
    unsigned u = *(const unsigned*)(hs + ev[c] * FD);
    upacc(u, a0, a1);
  }
  float inv = (e > s) ? 1.f / (float)(e - s) : 0.f;
  bf162_t o;
  o.x = __float2bfloat16(a0 * inv);
  o.y = __float2bfloat16(a1 * inv);
  *(bf162_t*)(mb + (size_t)node * FD + sl * 64 + sub * 2) = o;
}

// ---------------- fused weight transpose: dst[n][k] = sum of up to 3 W[k][n] ----------------
struct TSlots {
  int s0[14], s1[14], s2[14];
  unsigned long long o0[14], o1[14], o2[14];
};

__global__ void transpose_all_k(const void* p0, const void* p1, const void* p2, const void* p3,
                                const void* p4, const void* p5, TSlots ts,
                                bf16_t* __restrict__ BtAll, const int* flag) {
  int f = *flag;
  const void* bases[6] = {p0, p1, p2, p3, p4, p5};
  const int z = blockIdx.z;
  const void* s0 = bases[ts.s0[z]];
  const void* s1 = (ts.s1[z] >= 0) ? bases[ts.s1[z]] : nullptr;
  const void* s2 = (ts.s2[z] >= 0) ? bases[ts.s2[z]] : nullptr;
  const unsigned long long o0 = ts.o0[z], o1 = ts.o1[z], o2 = ts.o2[z];
  bf16_t* dst = BtAll + (size_t)z * FD * FD;
  __shared__ float tile[32][33];
  const int nb = blockIdx.x * 32;
  const int kb = blockIdx.y * 32;
  const int tx = threadIdx.x, ty = threadIdx.y;
  for (int j = 0; j < 32; j += 8) {
    size_t k = kb + ty + j, n = nb + tx;
    float v = ldf(s0, o0 + k * FD + n, f);
    if (s1) v += ldf(s1, o1 + k * FD + n, f);
    if (s2) v += ldf(s2, o2 + k * FD + n, f);
    tile[ty + j][tx] = v;
  }
  __syncthreads();
  for (int j = 0; j < 32; j += 8)
    dst[(size_t)(nb + ty + j) * FD + kb + tx] = __float2bfloat16(tile[tx][ty + j]);
}

__global__ void prep_bias_k(const void* b1, const void* b2, const void* pbd, const void* pbp,
                            float* __restrict__ out, const int* flag) {
  int f = *flag;
  for (int c = threadIdx.x; c < FD; c += 256) {
    out[0 * FD + c] = ldf(b1, 1 * FD + c, f);
    out[1 * FD + c] = ldf(b1, 0 * FD + c, f) + ldf(b1, 2 * FD + c, f) + ldf(b1, 3 * FD + c, f);
    out[2 * FD + c] = ldf(b2, 1 * FD + c, f);
    out[3 * FD + c] = ldf(b2, 0 * FD + c, f) + ldf(b2, 2 * FD + c, f) + ldf(b2, 3 * FD + c, f);
    out[4 * FD + c] = ldf(pbd, c, f);
    out[5 * FD + c] = ldf(pbp, c, f);
  }
}

// ---------------- multi-segment fused GEMM ----------------
// C[M,512] = sum_s A_s[Mpad,512] @ B_s[512,512]^T(stored [n][k]) + bias
// EPI 0: bf16 C + fused BN column stats (sum/sumsq of rounded values, atomics)
// EPI 1: output store (dtype by *oflag); blockIdx.z selects {A0,B0,half=0}/{A1,B1,half=1}
// XCD-bijective tile swizzle (m204): tile id = row*nbx+col; each XCD gets a
// contiguous chunk -> complete rows -> the shared A panel is fetched into ONE
// XCD L2 and reused by its 4 col-blocks (default round-robin dispatch spread
// the 4 col-blocks over 4 non-coherent L2s = 4x A traffic).
template <int NSEG, int EPI>
__global__ __launch_bounds__(256) void gemm_f(
    const bf16_t* __restrict__ A0, const bf16_t* __restrict__ A1,
    const bf16_t* __restrict__ A2, const bf16_t* __restrict__ A3,
    const bf16_t* __restrict__ B0, const bf16_t* __restrict__ B1,
    const bf16_t* __restrict__ B2, const bf16_t* __restrict__ B3,
    const float* __restrict__ bias, void* __restrict__ Cout, float* __restrict__ stats,
    int M, const int* oflag) {
  __shared__ __align__(16) short sA[128 * 32];
  __shared__ __align__(16) short sB[128 * 32];
  const int t = threadIdx.x;

  const int nbx = gridDim.x;
  const int nwg = nbx * gridDim.y;
  const int orig = blockIdx.y * nbx + blockIdx.x;
  const int qq = nwg >> 3, rr = nwg & 7;
  const int xc = orig & 7, kk = orig >> 3;
  const int wg = (xc < rr ? xc * (qq + 1) : rr * (qq + 1) + (xc - rr) * qq) + kk;
  const int n0 = (wg % nbx) * 128;
  const int m0 = (wg / nbx) * 128;

  const int lane = t & 63, w = t >> 6;
  const int wm = (w & 1) * 64, wn = (w >> 1) * 64;
  const int q = lane >> 4, r16 = lane & 15;

  const bf16_t* As[4] = {A0, A1, A2, A3};
  const bf16_t* Bs[4] = {B0, B1, B2, B3};
  const float* biasp = bias;
  int half = 0;
  int of32 = 0;
  if (EPI == 1) {
    of32 = *oflag;
    half = blockIdx.z;
    if (half) { As[0] = A1; Bs[0] = B1; }
    biasp = bias + half * FD;
  }

  f32x4 acc[4][4];
#pragma unroll
  for (int i = 0; i < 4; ++i)
#pragma unroll
    for (int j = 0; j < 4; ++j) acc[i][j] = (f32x4){0.f, 0.f, 0.f, 0.f};

  // staging: wave w fills rows [w*32, w*32+32); two glds per buffer (16 rows each)
  const int srow = w * 32 + (lane >> 2);
  const int schunk = (lane & 3) * 8;
  short* lA0 = sA + (w * 32) * 32;
  short* lA1 = sA + (w * 32 + 16) * 32;
  short* lB0 = sB + (w * 32) * 32;
  short* lB1 = sB + (w * 32 + 16) * 32;

#pragma unroll
  for (int seg = 0; seg < NSEG; ++seg) {
    const bf16_t* pa0 = As[seg] + (size_t)(m0 + srow) * FD + schunk;
    const bf16_t* pa1 = pa0 + (size_t)16 * FD;
    const bf16_t* pb0 = Bs[seg] + (size_t)(n0 + srow) * FD + schunk;
    const bf16_t* pb1 = pb0 + (size_t)16 * FD;
    for (int kb = 0; kb < 16; ++kb) {
      __syncthreads();
      glds16(pa0, lA0);
      glds16(pa1, lA1);
      glds16(pb0, lB0);
      glds16(pb1, lB1);
      pa0 += 32; pa1 += 32; pb0 += 32; pb1 += 32;
      __syncthreads();
      short8 af[4], bfr[4];
#pragma unroll
      for (int i = 0; i < 4; ++i) {
        af[i] = *(const short8*)(sA + (wm + i * 16 + r16) * 32 + q * 8);
        bfr[i] = *(const short8*)(sB + (wn + i * 16 + r16) * 32 + q * 8);
      }
#pragma unroll
      for (int i = 0; i < 4; ++i)
#pragma unroll
        for (int j = 0; j < 4; ++j)
          acc[i][j] = __builtin_amdgcn_mfma_f32_16x16x32_bf16(af[i], bfr[j], acc[i][j], 0, 0, 0);
    }
  }

  float bcol[4];
#pragma unroll
  for (int j = 0; j < 4; ++j) bcol[j] = biasp[n0 + wn + j * 16 + r16];

  if (EPI == 0) {
    bf16_t* Cb = (bf16_t*)Cout;
    float ps[4] = {0.f, 0.f, 0.f, 0.f}, pq[4] = {0.f, 0.f, 0.f, 0.f};
#pragma unroll
    for (int i = 0; i < 4; ++i) {
#pragma unroll
      for (int rg = 0; rg < 4; ++rg) {
        int gr = m0 + wm + i * 16 + q * 4 + rg;  // C/D: col=lane&15, row=(lane>>4)*4+reg
        if (gr >= M) continue;
#pragma unroll
        for (int j = 0; j < 4; ++j) {
          int col = n0 + wn + j * 16 + r16;
          bf16_t rb = __float2bfloat16(acc[i][j][rg] + bcol[j]);
          Cb[(size_t)gr * FD + col] = rb;
          float xr = __bfloat162float(rb);  // stats of the stored (rounded) tensor
          ps[j] += xr;
          pq[j] += xr * xr;
        }
      }
    }
#pragma unroll
    for (int j = 0; j < 4; ++j) {
      float s = ps[j], qq2 = pq[j];
      s += __shfl_xor(s, 16);
      s += __shfl_xor(s, 32);
      qq2 += __shfl_xor(qq2, 16);
      qq2 += __shfl_xor(qq2, 32);
      if (q == 0) {
        int col = n0 + wn + j * 16 + r16;
        atomicAdd(&stats[col], s);
        atomicAdd(&stats[FD + col], qq2);
      }
    }
  } else {
    float* outf = (float*)Cout + (size_t)half * M * FD;
    bf16_t* outb = (bf16_t*)Cout + (size_t)half * M * FD;
#pragma unroll
    for (int i = 0; i < 4; ++i) {
#pragma unroll
      for (int rg = 0; rg < 4; ++rg) {
        int gr = m0 + wm + i * 16 + q * 4 + rg;
        if (gr >= M) continue;
#pragma unroll
        for (int j = 0; j < 4; ++j) {
          int col = n0 + wn + j * 16 + r16;
          float y = acc[i][j][rg] + bcol[j];
          if (of32)
            outf[(size_t)gr * FD + col] = y;
          else
            outb[(size_t)gr * FD + col] = __float2bfloat16(y);
        }
      }
    }
  }
}

// ---------------- BN finalize + apply ----------------
__global__ void bn_fin_k(const float* __restrict__ stats, const void* gamma, const void* beta,
                         unsigned long long goff, float M, float* __restrict__ scsh,
                         const int* flag) {
  int f = *flag;
  for (int c = threadIdx.x; c < FD; c += 256) {
    float m = stats[c] / M;
    float v = fmaxf(stats[FD + c] / M - m * m, 0.f);
    float sc = ldf(gamma, goff + c, f) * rsqrtf(v + 1e-5f);
    scsh[c] = sc;
    scsh[FD + c] = ldf(beta, goff + c, f) - m * sc;
  }
}

__global__ void bn_apply_k(const bf16_t* __restrict__ x, const float* __restrict__ scsh,
                           bf16_t* __restrict__ out, int total8) {
  int p = blockIdx.x * 256 + threadIdx.x;
  if (p >= total8) return;
  int e = p * 8;
  int col = e & (FD - 1);
  uint4 u = *(const uint4*)(x + e);
  bf162_t* pr = (bf162_t*)&u;
  uint4 ov;
  bf162_t* po = (bf162_t*)&ov;
#pragma unroll
  for (int i = 0; i < 4; ++i) {
    float x0 = __bfloat162float(pr[i].x) * scsh[col + 2 * i] + scsh[FD + col + 2 * i];
    float x1 = __bfloat162float(pr[i].y) * scsh[col + 2 * i + 1] + scsh[FD + col + 2 * i + 1];
    po[i].x = __float2bfloat16(fmaxf(0.f, x0));
    po[i].y = __float2bfloat16(fmaxf(0.f, x1));
  }
  *(uint4*)(out + e) = ov;
}

// ---------------- host orchestration ----------------
extern "C" void kernel_launch(void* const* d_in, const int* in_sizes, int n_in,
                              void* d_out, int out_size, void* d_ws, size_t ws_size,
                              hipStream_t stream) {
  const int Mn = in_sizes[0] / FD;          // 20000
  const int Mp = (Mn + 127) & ~127;         // 20096
  const int E = in_sizes[14];               // 320000
  const size_t SZ = (size_t)FD * FD;

  const void* hd_raw = d_in[0];
  const void* hp_raw = d_in[1];
  const void* Ws1 = d_in[2];
  const void* Wn1 = d_in[3];
  const void* b1 = d_in[4];
  const void* Ws2 = d_in[5];
  const void* Wn2 = d_in[6];
  const void* b2 = d_in[7];
  const void* bng = d_in[8];
  const void* bnb = d_in[9];
  const void* pWd = d_in[10];
  const void* pbd = d_in[11];
  const void* pWp = d_in[12];
  const void* pbp = d_in[13];
  const int* a_src = (const int*)d_in[14];
  const int* a_dst = (const int*)d_in[15];
  const int* i_src = (const int*)d_in[16];
  const int* i_dst = (const int*)d_in[17];

  char* wptr = (char*)d_ws;
  auto alloc = [&](size_t bytes) {
    char* p = wptr;
    wptr += (bytes + 255) & ~(size_t)255;
    return p;
  };
  bf16_t* Bt = (bf16_t*)alloc(14 * SZ * 2);
  float* biasf = (float*)alloc(6 * FD * 4);
  float* stats = (float*)alloc(4 * FD * 4);  // [sum_d|sq_d|sum_p|sq_p]
  float* scshd = (float*)alloc(2 * FD * 4);
  float* scshp = (float*)alloc(2 * FD * 4);
  int* dtflag = (int*)alloc(256);
  int* deg = (int*)alloc((size_t)4 * Mn * 4);
  int* offs = (int*)alloc((size_t)4 * (Mn + 1) * 4);
  int* curs = (int*)alloc((size_t)4 * Mn * 4);
  int* evals = (int*)alloc((size_t)4 * E * 4);
  bf16_t* accb = (bf16_t*)alloc((size_t)Mp * FD * 2);  // bf16 pre-BN tensor (shared d/p)
  bf16_t* h_d = (bf16_t*)alloc((size_t)Mp * FD * 2);
  bf16_t* h_p = (bf16_t*)alloc((size_t)Mp * FD * 2);
  bf16_t* mean0 = (bf16_t*)alloc((size_t)Mp * FD * 2);
  bf16_t* mean1 = (bf16_t*)alloc((size_t)Mp * FD * 2);
  bf16_t* mean2 = (bf16_t*)alloc((size_t)Mp * FD * 2);
  bf16_t* mean3 = (bf16_t*)alloc((size_t)Mp * FD * 2);

  detect_k<<<1, 256, 0, stream>>>((const unsigned int*)hd_raw, 4096, dtflag);
  const int nh = Mn * FD, nhp = Mp * FD;
  conv_h_k<<<dim3((nhp / 4 + 255) / 256, 2), 256, 0, stream>>>(hd_raw, hp_raw, h_d, h_p, nh, nhp,
                                                               dtflag);

  hipMemsetAsync(deg, 0, (size_t)4 * Mn * 4, stream);
  int eb = (E + 255) / 256;
  count_deg_k<<<eb, 256, 0, stream>>>(a_src, a_dst, i_src, i_dst, deg, Mn, E);
  scan_k<<<4, 256, 0, stream>>>(deg, offs, curs, Mn);
  fill_k<<<dim3(eb, 4), 256, 0, stream>>>(a_src, a_dst, i_src, i_dst, curs, evals, Mn, E);

  // Bt slots: [0..3]=Wn1T[r], [4..7]=Wn2T[r], [8]=Ws1(0+2+3)T, [9]=Ws1(1)T,
  //           [10]=Ws2(0+2+3)T, [11]=Ws2(1)T, [12]=projWdT, [13]=projWpT
  TSlots ts;
  for (int z = 0; z < 14; ++z) { ts.s1[z] = -1; ts.s2[z] = -1; ts.o1[z] = 0; ts.o2[z] = 0; }
  for (int r = 0; r < 4; ++r) { ts.s0[r] = 1; ts.o0[r] = (unsigned long long)r * SZ; }
  for (int r = 0; r < 4; ++r) { ts.s0[4 + r] = 3; ts.o0[4 + r] = (unsigned long long)r * SZ; }
  ts.s0[8] = 0; ts.o0[8] = 0; ts.s1[8] = 0; ts.o1[8] = 2 * SZ; ts.s2[8] = 0; ts.o2[8] = 3 * SZ;
  ts.s0[9] = 0; ts.o0[9] = 1 * SZ;
  ts.s0[10] = 2; ts.o0[10] = 0; ts.s1[10] = 2; ts.o1[10] = 2 * SZ; ts.s2[10] = 2; ts.o2[10] = 3 * SZ;
  ts.s0[11] = 2; ts.o0[11] = 1 * SZ;
  ts.s0[12] = 4; ts.o0[12] = 0;
  ts.s0[13] = 5; ts.o0[13] = 0;
  transpose_all_k<<<dim3(16, 16, 14), dim3(32, 8), 0, stream>>>(Ws1, Wn1, Ws2, Wn2, pWd, pWp,
                                                                ts, Bt, dtflag);
  prep_bias_k<<<1, 256, 0, stream>>>(b1, b2, pbd, pbp, biasf, dtflag);

  dim3 ggrid(4, Mp / 128);
  dim3 sgrid(Mp / 8, 32);  // x = node-group (8 nodes/block), y = (rel,slice) pass
  const int bn8 = (Mn * FD / 8 + 255) / 256;

  auto layer = [&](int wn0, int wsp, int wsd, const float* bd, const float* bp,
                   unsigned long long goff_d, unsigned long long goff_p) {
    seg_mean_sl_k<<<sgrid, 256, 0, stream>>>(h_d, h_p, offs, evals, Mn, E, mean0, mean1,
                                             mean2, mean3);
    hipMemsetAsync(stats, 0, 4 * FD * 4, stream);
    // disease = hd@Ws[1] + mean1@Wn[1] + b   (K-concat, 2 segments)
    gemm_f<2, 0><<<ggrid, 256, 0, stream>>>(h_d, mean1, nullptr, nullptr,
                                            Bt + (size_t)wsd * SZ, Bt + (size_t)(wn0 + 1) * SZ,
                                            nullptr, nullptr, bd, accb, stats, Mn, dtflag);
    bn_fin_k<<<1, 256, 0, stream>>>(stats, bng, bnb, goff_d, (float)Mn, scshd, dtflag);
    bn_apply_k<<<bn8, 256, 0, stream>>>(accb, scshd, h_d, Mn * FD / 8);
    // protein = hp@(Ws0+Ws2+Ws3) + mean0@Wn0 + mean2@Wn2 + mean3@Wn3 + b   (4 segments)
    gemm_f<4, 0><<<ggrid, 256, 0, stream>>>(h_p, mean0, mean2, mean3,
                                            Bt + (size_t)wsp * SZ, Bt + (size_t)(wn0 + 0) * SZ,
                                            Bt + (size_t)(wn0 + 2) * SZ,
                                            Bt + (size_t)(wn0 + 3) * SZ, bp, accb,
                                            stats + 2 * FD, Mn, dtflag);
    bn_fin_k<<<1, 256, 0, stream>>>(stats + 2 * FD, bng, bnb, goff_p, (float)Mn, scshp, dtflag);
    bn_apply_k<<<bn8, 256, 0, stream>>>(accb, scshp, h_p, Mn * FD / 8);
  };

  // bn params layout [layer][ntype][512], ntype 0=disease 1=protein
  layer(0, 8, 9, biasf + 0 * FD, biasf + 1 * FD, 0ULL * FD, 1ULL * FD);
  layer(4, 10, 11, biasf + 2 * FD, biasf + 3 * FD, 2ULL * FD, 3ULL * FD);

  // merged final projections -> d_out (z=0: disease half, z=1: protein half)
  gemm_f<1, 1><<<dim3(4, Mp / 128, 2), 256, 0, stream>>>(
      h_d, h_p, nullptr, nullptr, Bt + 12 * SZ, Bt + 13 * SZ, nullptr, nullptr,
      biasf + 4 * FD, d_out, nullptr, Mn, dtflag);
}

// Round 2
// 941.677 us; speedup vs baseline: 1.2110x; 1.2110x over previous
//
#include <hip/hip_runtime.h>
#include <hip/hip_bf16.h>

typedef __attribute__((ext_vector_type(8))) short short8;
typedef __attribute__((ext_vector_type(4))) float f32x4;
using bf16_t = __hip_bfloat16;
using bf162_t = __hip_bfloat162;

#define FD 512

__device__ __forceinline__ float ldf(const void* p, size_t i, int f32) {
  return f32 ? ((const float*)p)[i] : __bfloat162float(((const bf16_t*)p)[i]);
}

// CK-pattern async global->LDS, 16B per lane (global_load_lds_dwordx4)
__device__ __forceinline__ void glds16(const bf16_t* g, short* l) {
  __builtin_amdgcn_global_load_lds(
      (const __attribute__((address_space(1))) unsigned int*)g,
      (__attribute__((address_space(3))) unsigned int*)(uintptr_t)l, 16, 0, 0);
}

// ---------------- dtype detect (fp32 vs bf16 device tensors) ----------------
__global__ void detect_k(const unsigned int* w, int nwords, int* flag) {
  __shared__ int cnt_s;
  if (threadIdx.x == 0) cnt_s = 0;
  __syncthreads();
  int c = 0;
  for (int i = threadIdx.x; i < nwords; i += 256) {
    unsigned lo = w[i] & 0xFFFFu;
    unsigned ex = (lo >> 7) & 0xFFu;
    if (lo == 0u || (ex >= 100u && ex <= 140u)) c++;
  }
  atomicAdd(&cnt_s, c);
  __syncthreads();
  if (threadIdx.x == 0) *flag = (2 * cnt_s < nwords) ? 1 : 0;
}

// convert h (z=0: disease, z=1: protein) to canonical bf16, zero pad rows
__global__ void conv_h_k(const void* s0, const void* s1, bf16_t* d0, bf16_t* d1, int n, int npad,
                         const int* flag) {
  int f = *flag;
  const void* src = blockIdx.y ? s1 : s0;
  bf16_t* dst = blockIdx.y ? d1 : d0;
  int e = (blockIdx.x * 256 + threadIdx.x) * 4;
  if (e >= npad) return;
  bf162_t o0, o1;
  if (e + 3 < n) {
    o0.x = __float2bfloat16(ldf(src, e + 0, f));
    o0.y = __float2bfloat16(ldf(src, e + 1, f));
    o1.x = __float2bfloat16(ldf(src, e + 2, f));
    o1.y = __float2bfloat16(ldf(src, e + 3, f));
  } else {
    float v[4];
    for (int u = 0; u < 4; ++u) v[u] = (e + u < n) ? ldf(src, e + u, f) : 0.f;
    o0.x = __float2bfloat16(v[0]); o0.y = __float2bfloat16(v[1]);
    o1.x = __float2bfloat16(v[2]); o1.y = __float2bfloat16(v[3]);
  }
  *(bf162_t*)(dst + e) = o0;
  *(bf162_t*)(dst + e + 2) = o1;
}

// ---------------- CSR build ----------------
__global__ void count_deg_k(const int* __restrict__ a_src, const int* __restrict__ a_dst,
                            const int* __restrict__ i_src, const int* __restrict__ i_dst,
                            int* __restrict__ deg, int M, int E) {
  int e = blockIdx.x * 256 + threadIdx.x;
  if (e >= E) return;
  atomicAdd(&deg[0 * M + a_dst[e]], 1);
  atomicAdd(&deg[1 * M + a_src[e]], 1);
  atomicAdd(&deg[2 * M + i_dst[e]], 1);
  atomicAdd(&deg[3 * M + i_src[e]], 1);
}

__global__ void scan_k(const int* __restrict__ deg, int* __restrict__ offs,
                       int* __restrict__ curs, int n) {
  const int r = blockIdx.x;
  const int* d = deg + r * n;
  int* off = offs + r * (n + 1);
  int* cur = curs + r * n;
  __shared__ int part[256];
  const int t = threadIdx.x;
  const int chunk = (n + 255) / 256;
  const int s0 = t * chunk;
  const int s1 = min(n, s0 + chunk);
  int sum = 0;
  for (int i = s0; i < s1; ++i) sum += d[i];
  part[t] = sum;
  __syncthreads();
  if (t == 0) {
    int run = 0;
    for (int i = 0; i < 256; ++i) { int v = part[i]; part[i] = run; run += v; }
  }
  __syncthreads();
  int run = part[t];
  for (int i = s0; i < s1; ++i) { off[i] = run; cur[i] = run; run += d[i]; }
  if (t == 255) off[n] = run;
}

__global__ void fill_k(const int* __restrict__ a_src, const int* __restrict__ a_dst,
                       const int* __restrict__ i_src, const int* __restrict__ i_dst,
                       int* __restrict__ curs, int* __restrict__ evals, int M, int E) {
  int r = blockIdx.y;
  int e = blockIdx.x * 256 + threadIdx.x;
  if (e >= E) return;
  const int* dsts[4] = {a_dst, a_src, i_dst, i_src};
  const int* vals[4] = {a_src, a_dst, i_src, i_dst};
  int d = dsts[r][e];
  int pos = atomicAdd(&curs[r * M + d], 1);
  evals[r * E + pos] = vals[r][e];
}

// ---------------- feature-sliced fused segment mean, 8-lane node groups ----------------
// 8 slices of 64 feats: (table, slice) working set = 20000*64*2B = 2.56 MB ->
// L2-resident per XCD (round-1: 90% L2 hit, FETCH 533->175 MB). Round-1 regression
// (4B/lane loads = 4x vmem instructions) fixed here: 8 lanes/node x 16B = one 128B
// row-slice; a wave gathers 8 nodes = 1KB per instruction (round-0 efficiency).
// Degree divergence across the 8 groups costs ~1.5x issue on the loop, no extra
// memory traffic (masked lanes don't fetch).
// blockIdx.y = pass: y<24: rel=1+y%3 (gather h_p), sl=y/3 -> 3 rels share a slice;
//              y>=24: rel=0 (gather h_d), sl=y-24.
__global__ void seg_mean_g8_k(const bf16_t* __restrict__ hd, const bf16_t* __restrict__ hp,
                              const int* __restrict__ offs, const int* __restrict__ evals,
                              int Mn, int E,
                              bf16_t* __restrict__ m0b, bf16_t* __restrict__ m1b,
                              bf16_t* __restrict__ m2b, bf16_t* __restrict__ m3b) {
  const int y = blockIdx.y;
  int rel, sl;
  if (y < 24) { rel = 1 + y % 3; sl = y / 3; }
  else        { rel = 0;         sl = y - 24; }
  const bf16_t* __restrict__ h = (rel == 0) ? hd : hp;
  bf16_t* mb = (rel == 0) ? m0b : (rel == 1) ? m1b : (rel == 2) ? m2b : m3b;

  const int t = threadIdx.x;
  const int g = t >> 3, sub = t & 7;       // 32 node-groups per block, 8 lanes each
  const int node = blockIdx.x * 32 + g;    // grid.x = Mp/32; pad nodes write zeros
  int s = 0, e = 0;
  if (node < Mn) {
    const int* off = offs + rel * (Mn + 1) + node;
    s = off[0];
    e = off[1];
  }
  const int* __restrict__ ev = evals + (size_t)rel * E;
  const bf16_t* hs = h + sl * 64 + sub * 8;  // 16B per lane within the 128B slice

  float a[8] = {0.f, 0.f, 0.f, 0.f, 0.f, 0.f, 0.f, 0.f};
  int c = s;
  for (; c + 3 < e; c += 4) {  // 4 independent 1KB wave-gathers in flight
    int n0 = ev[c], n1 = ev[c + 1], n2 = ev[c + 2], n3 = ev[c + 3];
    uint4 u0 = *(const uint4*)(hs + (size_t)n0 * FD);
    uint4 u1 = *(const uint4*)(hs + (size_t)n1 * FD);
    uint4 u2 = *(const uint4*)(hs + (size_t)n2 * FD);
    uint4 u3 = *(const uint4*)(hs + (size_t)n3 * FD);
    bf162_t* p0 = (bf162_t*)&u0;
    bf162_t* p1 = (bf162_t*)&u1;
    bf162_t* p2 = (bf162_t*)&u2;
    bf162_t* p3 = (bf162_t*)&u3;
#pragma unroll
    for (int i = 0; i < 4; ++i) {
      a[2 * i] += __bfloat162float(p0[i].x) + __bfloat162float(p1[i].x) +
                  __bfloat162float(p2[i].x) + __bfloat162float(p3[i].x);
      a[2 * i + 1] += __bfloat162float(p0[i].y) + __bfloat162float(p1[i].y) +
                      __bfloat162float(p2[i].y) + __bfloat162float(p3[i].y);
    }
  }
  for (; c < e; ++c) {
    uint4 u = *(const uint4*)(hs + (size_t)ev[c] * FD);
    bf162_t* pr = (bf162_t*)&u;
#pragma unroll
    for (int i = 0; i < 4; ++i) {
      a[2 * i] += __bfloat162float(pr[i].x);
      a[2 * i + 1] += __bfloat162float(pr[i].y);
    }
  }
  float inv = (e > s) ? 1.f / (float)(e - s) : 0.f;
  uint4 ov;
  bf162_t* po = (bf162_t*)&ov;
#pragma unroll
  for (int i = 0; i < 4; ++i) {
    po[i].x = __float2bfloat16(a[2 * i] * inv);
    po[i].y = __float2bfloat16(a[2 * i + 1] * inv);
  }
  *(uint4*)(mb + (size_t)node * FD + sl * 64 + sub * 8) = ov;  // 128B/group coalesced
}

// ---------------- fused weight transpose: dst[n][k] = sum of up to 3 W[k][n] ----------------
struct TSlots {
  int s0[14], s1[14], s2[14];
  unsigned long long o0[14], o1[14], o2[14];
};

__global__ void transpose_all_k(const void* p0, const void* p1, const void* p2, const void* p3,
                                const void* p4, const void* p5, TSlots ts,
                                bf16_t* __restrict__ BtAll, const int* flag) {
  int f = *flag;
  const void* bases[6] = {p0, p1, p2, p3, p4, p5};
  const int z = blockIdx.z;
  const void* s0 = bases[ts.s0[z]];
  const void* s1 = (ts.s1[z] >= 0) ? bases[ts.s1[z]] : nullptr;
  const void* s2 = (ts.s2[z] >= 0) ? bases[ts.s2[z]] : nullptr;
  const unsigned long long o0 = ts.o0[z], o1 = ts.o1[z], o2 = ts.o2[z];
  bf16_t* dst = BtAll + (size_t)z * FD * FD;
  __shared__ float tile[32][33];
  const int nb = blockIdx.x * 32;
  const int kb = blockIdx.y * 32;
  const int tx = threadIdx.x, ty = threadIdx.y;
  for (int j = 0; j < 32; j += 8) {
    size_t k = kb + ty + j, n = nb + tx;
    float v = ldf(s0, o0 + k * FD + n, f);
    if (s1) v += ldf(s1, o1 + k * FD + n, f);
    if (s2) v += ldf(s2, o2 + k * FD + n, f);
    tile[ty + j][tx] = v;
  }
  __syncthreads();
  for (int j = 0; j < 32; j += 8)
    dst[(size_t)(nb + ty + j) * FD + kb + tx] = __float2bfloat16(tile[tx][ty + j]);
}

__global__ void prep_bias_k(const void* b1, const void* b2, const void* pbd, const void* pbp,
                            float* __restrict__ out, const int* flag) {
  int f = *flag;
  for (int c = threadIdx.x; c < FD; c += 256) {
    out[0 * FD + c] = ldf(b1, 1 * FD + c, f);
    out[1 * FD + c] = ldf(b1, 0 * FD + c, f) + ldf(b1, 2 * FD + c, f) + ldf(b1, 3 * FD + c, f);
    out[2 * FD + c] = ldf(b2, 1 * FD + c, f);
    out[3 * FD + c] = ldf(b2, 0 * FD + c, f) + ldf(b2, 2 * FD + c, f) + ldf(b2, 3 * FD + c, f);
    out[4 * FD + c] = ldf(pbd, c, f);
    out[5 * FD + c] = ldf(pbp, c, f);
  }
}

// ---------------- multi-segment fused GEMM ----------------
// C[M,512] = sum_s A_s[Mpad,512] @ B_s[512,512]^T(stored [n][k]) + bias
// EPI 0: bf16 C + fused BN column stats (sum/sumsq of rounded values, atomics)
// EPI 1: output store (dtype by *oflag); blockIdx.z selects {A0,B0,half=0}/{A1,B1,half=1}
// XCD-bijective tile swizzle (m204): each XCD owns contiguous runs of complete
// tile-rows -> the shared A panel lands in ONE XCD L2 and is reused by its
// col-blocks instead of being fetched by 4 non-coherent L2s.
template <int NSEG, int EPI>
__global__ __launch_bounds__(256) void gemm_f(
    const bf16_t* __restrict__ A0, const bf16_t* __restrict__ A1,
    const bf16_t* __restrict__ A2, const bf16_t* __restrict__ A3,
    const bf16_t* __restrict__ B0, const bf16_t* __restrict__ B1,
    const bf16_t* __restrict__ B2, const bf16_t* __restrict__ B3,
    const float* __restrict__ bias, void* __restrict__ Cout, float* __restrict__ stats,
    int M, const int* oflag) {
  __shared__ __align__(16) short sA[128 * 32];
  __shared__ __align__(16) short sB[128 * 32];
  const int t = threadIdx.x;

  const int nbx = gridDim.x;
  const int nwg = nbx * gridDim.y;
  const int orig = blockIdx.y * nbx + blockIdx.x;
  const int qq = nwg >> 3, rr = nwg & 7;
  const int xc = orig & 7, kk = orig >> 3;
  const int wg = (xc < rr ? xc * (qq + 1) : rr * (qq + 1) + (xc - rr) * qq) + kk;
  const int n0 = (wg % nbx) * 128;
  const int m0 = (wg / nbx) * 128;

  const int lane = t & 63, w = t >> 6;
  const int wm = (w & 1) * 64, wn = (w >> 1) * 64;
  const int q = lane >> 4, r16 = lane & 15;

  const bf16_t* As[4] = {A0, A1, A2, A3};
  const bf16_t* Bs[4] = {B0, B1, B2, B3};
  const float* biasp = bias;
  int half = 0;
  int of32 = 0;
  if (EPI == 1) {
    of32 = *oflag;
    half = blockIdx.z;
    if (half) { As[0] = A1; Bs[0] = B1; }
    biasp = bias + half * FD;
  }

  f32x4 acc[4][4];
#pragma unroll
  for (int i = 0; i < 4; ++i)
#pragma unroll
    for (int j = 0; j < 4; ++j) acc[i][j] = (f32x4){0.f, 0.f, 0.f, 0.f};

  // staging: wave w fills rows [w*32, w*32+32); two glds per buffer (16 rows each)
  const int srow = w * 32 + (lane >> 2);
  const int schunk = (lane & 3) * 8;
  short* lA0 = sA + (w * 32) * 32;
  short* lA1 = sA + (w * 32 + 16) * 32;
  short* lB0 = sB + (w * 32) * 32;
  short* lB1 = sB + (w * 32 + 16) * 32;

#pragma unroll
  for (int seg = 0; seg < NSEG; ++seg) {
    const bf16_t* pa0 = As[seg] + (size_t)(m0 + srow) * FD + schunk;
    const bf16_t* pa1 = pa0 + (size_t)16 * FD;
    const bf16_t* pb0 = Bs[seg] + (size_t)(n0 + srow) * FD + schunk;
    const bf16_t* pb1 = pb0 + (size_t)16 * FD;
    for (int kb = 0; kb < 16; ++kb) {
      __syncthreads();
      glds16(pa0, lA0);
      glds16(pa1, lA1);
      glds16(pb0, lB0);
      glds16(pb1, lB1);
      pa0 += 32; pa1 += 32; pb0 += 32; pb1 += 32;
      __syncthreads();
      short8 af[4], bfr[4];
#pragma unroll
      for (int i = 0; i < 4; ++i) {
        af[i] = *(const short8*)(sA + (wm + i * 16 + r16) * 32 + q * 8);
        bfr[i] = *(const short8*)(sB + (wn + i * 16 + r16) * 32 + q * 8);
      }
#pragma unroll
      for (int i = 0; i < 4; ++i)
#pragma unroll
        for (int j = 0; j < 4; ++j)
          acc[i][j] = __builtin_amdgcn_mfma_f32_16x16x32_bf16(af[i], bfr[j], acc[i][j], 0, 0, 0);
    }
  }

  float bcol[4];
#pragma unroll
  for (int j = 0; j < 4; ++j) bcol[j] = biasp[n0 + wn + j * 16 + r16];

  if (EPI == 0) {
    bf16_t* Cb = (bf16_t*)Cout;
    float ps[4] = {0.f, 0.f, 0.f, 0.f}, pq[4] = {0.f, 0.f, 0.f, 0.f};
#pragma unroll
    for (int i = 0; i < 4; ++i) {
#pragma unroll
      for (int rg = 0; rg < 4; ++rg) {
        int gr = m0 + wm + i * 16 + q * 4 + rg;  // C/D: col=lane&15, row=(lane>>4)*4+reg
        if (gr >= M) continue;
#pragma unroll
        for (int j = 0; j < 4; ++j) {
          int col = n0 + wn + j * 16 + r16;
          bf16_t rb = __float2bfloat16(acc[i][j][rg] + bcol[j]);
          Cb[(size_t)gr * FD + col] = rb;
          float xr = __bfloat162float(rb);  // stats of the stored (rounded) tensor
          ps[j] += xr;
          pq[j] += xr * xr;
        }
      }
    }
#pragma unroll
    for (int j = 0; j < 4; ++j) {
      float s = ps[j], qq2 = pq[j];
      s += __shfl_xor(s, 16);
      s += __shfl_xor(s, 32);
      qq2 += __shfl_xor(qq2, 16);
      qq2 += __shfl_xor(qq2, 32);
      if (q == 0) {
        int col = n0 + wn + j * 16 + r16;
        atomicAdd(&stats[col], s);
        atomicAdd(&stats[FD + col], qq2);
      }
    }
  } else {
    float* outf = (float*)Cout + (size_t)half * M * FD;
    bf16_t* outb = (bf16_t*)Cout + (size_t)half * M * FD;
#pragma unroll
    for (int i = 0; i < 4; ++i) {
#pragma unroll
      for (int rg = 0; rg < 4; ++rg) {
        int gr = m0 + wm + i * 16 + q * 4 + rg;
        if (gr >= M) continue;
#pragma unroll
        for (int j = 0; j < 4; ++j) {
          int col = n0 + wn + j * 16 + r16;
          float y = acc[i][j][rg] + bcol[j];
          if (of32)
            outf[(size_t)gr * FD + col] = y;
          else
            outb[(size_t)gr * FD + col] = __float2bfloat16(y);
        }
      }
    }
  }
}

// ---------------- BN finalize + apply ----------------
__global__ void bn_fin_k(const float* __restrict__ stats, const void* gamma, const void* beta,
                         unsigned long long goff, float M, float* __restrict__ scsh,
                         const int* flag) {
  int f = *flag;
  for (int c = threadIdx.x; c < FD; c += 256) {
    float m = stats[c] / M;
    float v = fmaxf(stats[FD + c] / M - m * m, 0.f);
    float sc = ldf(gamma, goff + c, f) * rsqrtf(v + 1e-5f);
    scsh[c] = sc;
    scsh[FD + c] = ldf(beta, goff + c, f) - m * sc;
  }
}

__global__ void bn_apply_k(const bf16_t* __restrict__ x, const float* __restrict__ scsh,
                           bf16_t* __restrict__ out, int total8) {
  int p = blockIdx.x * 256 + threadIdx.x;
  if (p >= total8) return;
  int e = p * 8;
  int col = e & (FD - 1);
  uint4 u = *(const uint4*)(x + e);
  bf162_t* pr = (bf162_t*)&u;
  uint4 ov;
  bf162_t* po = (bf162_t*)&ov;
#pragma unroll
  for (int i = 0; i < 4; ++i) {
    float x0 = __bfloat162float(pr[i].x) * scsh[col + 2 * i] + scsh[FD + col + 2 * i];
    float x1 = __bfloat162float(pr[i].y) * scsh[col + 2 * i + 1] + scsh[FD + col + 2 * i + 1];
    po[i].x = __float2bfloat16(fmaxf(0.f, x0));
    po[i].y = __float2bfloat16(fmaxf(0.f, x1));
  }
  *(uint4*)(out + e) = ov;
}

// ---------------- host orchestration ----------------
extern "C" void kernel_launch(void* const* d_in, const int* in_sizes, int n_in,
                              void* d_out, int out_size, void* d_ws, size_t ws_size,
                              hipStream_t stream) {
  const int Mn = in_sizes[0] / FD;          // 20000
  const int Mp = (Mn + 127) & ~127;         // 20096
  const int E = in_sizes[14];               // 320000
  const size_t SZ = (size_t)FD * FD;

  const void* hd_raw = d_in[0];
  const void* hp_raw = d_in[1];
  const void* Ws1 = d_in[2];
  const void* Wn1 = d_in[3];
  const void* b1 = d_in[4];
  const void* Ws2 = d_in[5];
  const void* Wn2 = d_in[6];
  const void* b2 = d_in[7];
  const void* bng = d_in[8];
  const void* bnb = d_in[9];
  const void* pWd = d_in[10];
  const void* pbd = d_in[11];
  const void* pWp = d_in[12];
  const void* pbp = d_in[13];
  const int* a_src = (const int*)d_in[14];
  const int* a_dst = (const int*)d_in[15];
  const int* i_src = (const int*)d_in[16];
  const int* i_dst = (const int*)d_in[17];

  char* wptr = (char*)d_ws;
  auto alloc = [&](size_t bytes) {
    char* p = wptr;
    wptr += (bytes + 255) & ~(size_t)255;
    return p;
  };
  bf16_t* Bt = (bf16_t*)alloc(14 * SZ * 2);
  float* biasf = (float*)alloc(6 * FD * 4);
  float* stats = (float*)alloc(4 * FD * 4);  // [sum_d|sq_d|sum_p|sq_p]
  float* scshd = (float*)alloc(2 * FD * 4);
  float* scshp = (float*)alloc(2 * FD * 4);
  int* dtflag = (int*)alloc(256);
  int* deg = (int*)alloc((size_t)4 * Mn * 4);
  int* offs = (int*)alloc((size_t)4 * (Mn + 1) * 4);
  int* curs = (int*)alloc((size_t)4 * Mn * 4);
  int* evals = (int*)alloc((size_t)4 * E * 4);
  bf16_t* accb = (bf16_t*)alloc((size_t)Mp * FD * 2);  // bf16 pre-BN tensor (shared d/p)
  bf16_t* h_d = (bf16_t*)alloc((size_t)Mp * FD * 2);
  bf16_t* h_p = (bf16_t*)alloc((size_t)Mp * FD * 2);
  bf16_t* mean0 = (bf16_t*)alloc((size_t)Mp * FD * 2);
  bf16_t* mean1 = (bf16_t*)alloc((size_t)Mp * FD * 2);
  bf16_t* mean2 = (bf16_t*)alloc((size_t)Mp * FD * 2);
  bf16_t* mean3 = (bf16_t*)alloc((size_t)Mp * FD * 2);

  detect_k<<<1, 256, 0, stream>>>((const unsigned int*)hd_raw, 4096, dtflag);
  const int nh = Mn * FD, nhp = Mp * FD;
  conv_h_k<<<dim3((nhp / 4 + 255) / 256, 2), 256, 0, stream>>>(hd_raw, hp_raw, h_d, h_p, nh, nhp,
                                                               dtflag);

  hipMemsetAsync(deg, 0, (size_t)4 * Mn * 4, stream);
  int eb = (E + 255) / 256;
  count_deg_k<<<eb, 256, 0, stream>>>(a_src, a_dst, i_src, i_dst, deg, Mn, E);
  scan_k<<<4, 256, 0, stream>>>(deg, offs, curs, Mn);
  fill_k<<<dim3(eb, 4), 256, 0, stream>>>(a_src, a_dst, i_src, i_dst, curs, evals, Mn, E);

  // Bt slots: [0..3]=Wn1T[r], [4..7]=Wn2T[r], [8]=Ws1(0+2+3)T, [9]=Ws1(1)T,
  //           [10]=Ws2(0+2+3)T, [11]=Ws2(1)T, [12]=projWdT, [13]=projWpT
  TSlots ts;
  for (int z = 0; z < 14; ++z) { ts.s1[z] = -1; ts.s2[z] = -1; ts.o1[z] = 0; ts.o2[z] = 0; }
  for (int r = 0; r < 4; ++r) { ts.s0[r] = 1; ts.o0[r] = (unsigned long long)r * SZ; }
  for (int r = 0; r < 4; ++r) { ts.s0[4 + r] = 3; ts.o0[4 + r] = (unsigned long long)r * SZ; }
  ts.s0[8] = 0; ts.o0[8] = 0; ts.s1[8] = 0; ts.o1[8] = 2 * SZ; ts.s2[8] = 0; ts.o2[8] = 3 * SZ;
  ts.s0[9] = 0; ts.o0[9] = 1 * SZ;
  ts.s0[10] = 2; ts.o0[10] = 0; ts.s1[10] = 2; ts.o1[10] = 2 * SZ; ts.s2[10] = 2; ts.o2[10] = 3 * SZ;
  ts.s0[11] = 2; ts.o0[11] = 1 * SZ;
  ts.s0[12] = 4; ts.o0[12] = 0;
  ts.s0[13] = 5; ts.o0[13] = 0;
  transpose_all_k<<<dim3(16, 16, 14), dim3(32, 8), 0, stream>>>(Ws1, Wn1, Ws2, Wn2, pWd, pWp,
                                                                ts, Bt, dtflag);
  prep_bias_k<<<1, 256, 0, stream>>>(b1, b2, pbd, pbp, biasf, dtflag);

  dim3 ggrid(4, Mp / 128);
  dim3 sgrid(Mp / 32, 32);  // x = node-group (32 nodes/block), y = (rel,slice) pass
  const int bn8 = (Mn * FD / 8 + 255) / 256;

  auto layer = [&](int wn0, int wsp, int wsd, const float* bd, const float* bp,
                   unsigned long long goff_d, unsigned long long goff_p) {
    seg_mean_g8_k<<<sgrid, 256, 0, stream>>>(h_d, h_p, offs, evals, Mn, E, mean0, mean1,
                                             mean2, mean3);
    hipMemsetAsync(stats, 0, 4 * FD * 4, stream);
    // disease = hd@Ws[1] + mean1@Wn[1] + b   (K-concat, 2 segments)
    gemm_f<2, 0><<<ggrid, 256, 0, stream>>>(h_d, mean1, nullptr, nullptr,
                                            Bt + (size_t)wsd * SZ, Bt + (size_t)(wn0 + 1) * SZ,
                                            nullptr, nullptr, bd, accb, stats, Mn, dtflag);
    bn_fin_k<<<1, 256, 0, stream>>>(stats, bng, bnb, goff_d, (float)Mn, scshd, dtflag);
    bn_apply_k<<<bn8, 256, 0, stream>>>(accb, scshd, h_d, Mn * FD / 8);
    // protein = hp@(Ws0+Ws2+Ws3) + mean0@Wn0 + mean2@Wn2 + mean3@Wn3 + b   (4 segments)
    gemm_f<4, 0><<<ggrid, 256, 0, stream>>>(h_p, mean0, mean2, mean3,
                                            Bt + (size_t)wsp * SZ, Bt + (size_t)(wn0 + 0) * SZ,
                                            Bt + (size_t)(wn0 + 2) * SZ,
                                            Bt + (size_t)(wn0 + 3) * SZ, bp, accb,
                                            stats + 2 * FD, Mn, dtflag);
    bn_fin_k<<<1, 256, 0, stream>>>(stats + 2 * FD, bng, bnb, goff_p, (float)Mn, scshp, dtflag);
    bn_apply_k<<<bn8, 256, 0, stream>>>(accb, scshp, h_p, Mn * FD / 8);
  };

  // bn params layout [layer][ntype][512], ntype 0=disease 1=protein
  layer(0, 8, 9, biasf + 0 * FD, biasf + 1 * FD, 0ULL * FD, 1ULL * FD);
  layer(4, 10, 11, biasf + 2 * FD, biasf + 3 * FD, 2ULL * FD, 3ULL * FD);

  // merged final projections -> d_out (z=0: disease half, z=1: protein half)
  gemm_f<1, 1><<<dim3(4, Mp / 128, 2), 256, 0, stream>>>(
      h_d, h_p, nullptr, nullptr, Bt + 12 * SZ, Bt + 13 * SZ, nullptr, nullptr,
      biasf + 4 * FD, d_out, nullptr, Mn, dtflag);
}

// Round 4
// 874.277 us; speedup vs baseline: 1.3043x; 1.0771x over previous
//
#include <hip/hip_runtime.h>
#include <hip/hip_bf16.h>

typedef __attribute__((ext_vector_type(8))) short short8;
typedef __attribute__((ext_vector_type(4))) float f32x4;
using bf16_t = __hip_bfloat16;
using bf162_t = __hip_bfloat162;

#define FD 512

__device__ __forceinline__ float ldf(const void* p, size_t i, int f32) {
  return f32 ? ((const float*)p)[i] : __bfloat162float(((const bf16_t*)p)[i]);
}

// CK-pattern async global->LDS, 16B per lane (global_load_lds_dwordx4)
__device__ __forceinline__ void glds16(const bf16_t* g, short* l) {
  __builtin_amdgcn_global_load_lds(
      (const __attribute__((address_space(1))) unsigned int*)g,
      (__attribute__((address_space(3))) unsigned int*)(uintptr_t)l, 16, 0, 0);
}

// ---------------- dtype detect (fp32 vs bf16 device tensors) ----------------
__global__ void detect_k(const unsigned int* w, int nwords, int* flag) {
  __shared__ int cnt_s;
  if (threadIdx.x == 0) cnt_s = 0;
  __syncthreads();
  int c = 0;
  for (int i = threadIdx.x; i < nwords; i += 256) {
    unsigned lo = w[i] & 0xFFFFu;
    unsigned ex = (lo >> 7) & 0xFFu;
    if (lo == 0u || (ex >= 100u && ex <= 140u)) c++;
  }
  atomicAdd(&cnt_s, c);
  __syncthreads();
  if (threadIdx.x == 0) *flag = (2 * cnt_s < nwords) ? 1 : 0;
}

// convert h (z=0: disease, z=1: protein) to canonical bf16, zero pad rows
__global__ void conv_h_k(const void* s0, const void* s1, bf16_t* d0, bf16_t* d1, int n, int npad,
                         const int* flag) {
  int f = *flag;
  const void* src = blockIdx.y ? s1 : s0;
  bf16_t* dst = blockIdx.y ? d1 : d0;
  int e = (blockIdx.x * 256 + threadIdx.x) * 4;
  if (e >= npad) return;
  bf162_t o0, o1;
  if (e + 3 < n) {
    o0.x = __float2bfloat16(ldf(src, e + 0, f));
    o0.y = __float2bfloat16(ldf(src, e + 1, f));
    o1.x = __float2bfloat16(ldf(src, e + 2, f));
    o1.y = __float2bfloat16(ldf(src, e + 3, f));
  } else {
    float v[4];
    for (int u = 0; u < 4; ++u) v[u] = (e + u < n) ? ldf(src, e + u, f) : 0.f;
    o0.x = __float2bfloat16(v[0]); o0.y = __float2bfloat16(v[1]);
    o1.x = __float2bfloat16(v[2]); o1.y = __float2bfloat16(v[3]);
  }
  *(bf162_t*)(dst + e) = o0;
  *(bf162_t*)(dst + e + 2) = o1;
}

// ---------------- CSR build ----------------
__global__ void count_deg_k(const int* __restrict__ a_src, const int* __restrict__ a_dst,
                            const int* __restrict__ i_src, const int* __restrict__ i_dst,
                            int* __restrict__ deg, int M, int E) {
  int e = blockIdx.x * 256 + threadIdx.x;
  if (e >= E) return;
  atomicAdd(&deg[0 * M + a_dst[e]], 1);
  atomicAdd(&deg[1 * M + a_src[e]], 1);
  atomicAdd(&deg[2 * M + i_dst[e]], 1);
  atomicAdd(&deg[3 * M + i_src[e]], 1);
}

__global__ void scan_k(const int* __restrict__ deg, int* __restrict__ offs,
                       int* __restrict__ curs, int n) {
  const int r = blockIdx.x;
  const int* d = deg + r * n;
  int* off = offs + r * (n + 1);
  int* cur = curs + r * n;
  __shared__ int part[256];
  const int t = threadIdx.x;
  const int chunk = (n + 255) / 256;
  const int s0 = t * chunk;
  const int s1 = min(n, s0 + chunk);
  int sum = 0;
  for (int i = s0; i < s1; ++i) sum += d[i];
  part[t] = sum;
  __syncthreads();
  if (t == 0) {
    int run = 0;
    for (int i = 0; i < 256; ++i) { int v = part[i]; part[i] = run; run += v; }
  }
  __syncthreads();
  int run = part[t];
  for (int i = s0; i < s1; ++i) { off[i] = run; cur[i] = run; run += d[i]; }
  if (t == 255) off[n] = run;
}

__global__ void fill_k(const int* __restrict__ a_src, const int* __restrict__ a_dst,
                       const int* __restrict__ i_src, const int* __restrict__ i_dst,
                       int* __restrict__ curs, int* __restrict__ evals, int M, int E) {
  int r = blockIdx.y;
  int e = blockIdx.x * 256 + threadIdx.x;
  if (e >= E) return;
  const int* dsts[4] = {a_dst, a_src, i_dst, i_src};
  const int* vals[4] = {a_src, a_dst, i_src, i_dst};
  int d = dsts[r][e];
  int pos = atomicAdd(&curs[r * M + d], 1);
  evals[r * E + pos] = vals[r][e];
}

// ---------------- feature-sliced fused segment mean, 8-lane node groups ----------------
// 8 slices of 64 feats: (table, slice) working set = 2.56 MB -> L2-resident per XCD
// (round-1: FETCH 533->175 MB). 8 lanes/node x 16B = 128B row-slice; a wave gathers
// 8 nodes = 1KB per instruction. Round-2 measured: 106 us/dispatch, VALU-bound 61%.
__global__ void seg_mean_g8_k(const bf16_t* __restrict__ hd, const bf16_t* __restrict__ hp,
                              const int* __restrict__ offs, const int* __restrict__ evals,
                              int Mn, int E,
                              bf16_t* __restrict__ m0b, bf16_t* __restrict__ m1b,
                              bf16_t* __restrict__ m2b, bf16_t* __restrict__ m3b) {
  const int y = blockIdx.y;
  int rel, sl;
  if (y < 24) { rel = 1 + y % 3; sl = y / 3; }
  else        { rel = 0;         sl = y - 24; }
  const bf16_t* __restrict__ h = (rel == 0) ? hd : hp;
  bf16_t* mb = (rel == 0) ? m0b : (rel == 1) ? m1b : (rel == 2) ? m2b : m3b;

  const int t = threadIdx.x;
  const int g = t >> 3, sub = t & 7;       // 32 node-groups per block, 8 lanes each
  const int node = blockIdx.x * 32 + g;    // grid.x = Mp/32; pad nodes write zeros
  int s = 0, e = 0;
  if (node < Mn) {
    const int* off = offs + rel * (Mn + 1) + node;
    s = off[0];
    e = off[1];
  }
  const int* __restrict__ ev = evals + (size_t)rel * E;
  const bf16_t* hs = h + sl * 64 + sub * 8;  // 16B per lane within the 128B slice

  float a[8] = {0.f, 0.f, 0.f, 0.f, 0.f, 0.f, 0.f, 0.f};
  int c = s;
  for (; c + 3 < e; c += 4) {  // 4 independent 1KB wave-gathers in flight
    int n0 = ev[c], n1 = ev[c + 1], n2 = ev[c + 2], n3 = ev[c + 3];
    uint4 u0 = *(const uint4*)(hs + (size_t)n0 * FD);
    uint4 u1 = *(const uint4*)(hs + (size_t)n1 * FD);
    uint4 u2 = *(const uint4*)(hs + (size_t)n2 * FD);
    uint4 u3 = *(const uint4*)(hs + (size_t)n3 * FD);
    bf162_t* p0 = (bf162_t*)&u0;
    bf162_t* p1 = (bf162_t*)&u1;
    bf162_t* p2 = (bf162_t*)&u2;
    bf162_t* p3 = (bf162_t*)&u3;
#pragma unroll
    for (int i = 0; i < 4; ++i) {
      a[2 * i] += __bfloat162float(p0[i].x) + __bfloat162float(p1[i].x) +
                  __bfloat162float(p2[i].x) + __bfloat162float(p3[i].x);
      a[2 * i + 1] += __bfloat162float(p0[i].y) + __bfloat162float(p1[i].y) +
                      __bfloat162float(p2[i].y) + __bfloat162float(p3[i].y);
    }
  }
  for (; c < e; ++c) {
    uint4 u = *(const uint4*)(hs + (size_t)ev[c] * FD);
    bf162_t* pr = (bf162_t*)&u;
#pragma unroll
    for (int i = 0; i < 4; ++i) {
      a[2 * i] += __bfloat162float(pr[i].x);
      a[2 * i + 1] += __bfloat162float(pr[i].y);
    }
  }
  float inv = (e > s) ? 1.f / (float)(e - s) : 0.f;
  uint4 ov;
  bf162_t* po = (bf162_t*)&ov;
#pragma unroll
  for (int i = 0; i < 4; ++i) {
    po[i].x = __float2bfloat16(a[2 * i] * inv);
    po[i].y = __float2bfloat16(a[2 * i + 1] * inv);
  }
  *(uint4*)(mb + (size_t)node * FD + sl * 64 + sub * 8) = ov;  // 128B/group coalesced
}

// ---------------- fused weight transpose: dst[n][k] = sum of up to 3 W[k][n] ----------------
struct TSlots {
  int s0[14], s1[14], s2[14];
  unsigned long long o0[14], o1[14], o2[14];
};

__global__ void transpose_all_k(const void* p0, const void* p1, const void* p2, const void* p3,
                                const void* p4, const void* p5, TSlots ts,
                                bf16_t* __restrict__ BtAll, const int* flag) {
  int f = *flag;
  const void* bases[6] = {p0, p1, p2, p3, p4, p5};
  const int z = blockIdx.z;
  const void* s0 = bases[ts.s0[z]];
  const void* s1 = (ts.s1[z] >= 0) ? bases[ts.s1[z]] : nullptr;
  const void* s2 = (ts.s2[z] >= 0) ? bases[ts.s2[z]] : nullptr;
  const unsigned long long o0 = ts.o0[z], o1 = ts.o1[z], o2 = ts.o2[z];
  bf16_t* dst = BtAll + (size_t)z * FD * FD;
  __shared__ float tile[32][33];
  const int nb = blockIdx.x * 32;
  const int kb = blockIdx.y * 32;
  const int tx = threadIdx.x, ty = threadIdx.y;
  for (int j = 0; j < 32; j += 8) {
    size_t k = kb + ty + j, n = nb + tx;
    float v = ldf(s0, o0 + k * FD + n, f);
    if (s1) v += ldf(s1, o1 + k * FD + n, f);
    if (s2) v += ldf(s2, o2 + k * FD + n, f);
    tile[ty + j][tx] = v;
  }
  __syncthreads();
  for (int j = 0; j < 32; j += 8)
    dst[(size_t)(nb + ty + j) * FD + kb + tx] = __float2bfloat16(tile[tx][ty + j]);
}

__global__ void prep_bias_k(const void* b1, const void* b2, const void* pbd, const void* pbp,
                            float* __restrict__ out, const int* flag) {
  int f = *flag;
  for (int c = threadIdx.x; c < FD; c += 256) {
    out[0 * FD + c] = ldf(b1, 1 * FD + c, f);
    out[1 * FD + c] = ldf(b1, 0 * FD + c, f) + ldf(b1, 2 * FD + c, f) + ldf(b1, 3 * FD + c, f);
    out[2 * FD + c] = ldf(b2, 1 * FD + c, f);
    out[3 * FD + c] = ldf(b2, 0 * FD + c, f) + ldf(b2, 2 * FD + c, f) + ldf(b2, 3 * FD + c, f);
    out[4 * FD + c] = ldf(pbd, c, f);
    out[5 * FD + c] = ldf(pbp, c, f);
  }
}

// ---------------- multi-segment fused GEMM, 2-phase LDS double-buffer ----------------
// C[M,512] = sum_s A_s[Mpad,512] @ B_s[512,512]^T(stored [n][k]) + bias
// T3-minimum pipeline: stage tile t+1 into the ping buffer BEFORE computing tile t;
// ONE __syncthreads per k-step (its implicit vmcnt(0) drain is the load wait).
// Replaces the 0-phase {barrier, glds, barrier, compute} which exposed full load
// latency every k-step and paid 2 barriers.
// EPI 0: bf16 C + fused BN column stats; EPI 1: output store (dtype by *oflag).
// XCD-bijective tile swizzle (m204) retained for A-panel L2 locality.
template <int NSEG, int EPI>
__global__ __launch_bounds__(256) void gemm_f(
    const bf16_t* __restrict__ A0, const bf16_t* __restrict__ A1,
    const bf16_t* __restrict__ A2, const bf16_t* __restrict__ A3,
    const bf16_t* __restrict__ B0, const bf16_t* __restrict__ B1,
    const bf16_t* __restrict__ B2, const bf16_t* __restrict__ B3,
    const float* __restrict__ bias, void* __restrict__ Cout, float* __restrict__ stats,
    int M, const int* oflag) {
  __shared__ __align__(16) short sA0[128 * 32];
  __shared__ __align__(16) short sB0[128 * 32];
  __shared__ __align__(16) short sA1[128 * 32];
  __shared__ __align__(16) short sB1[128 * 32];
  const int t = threadIdx.x;

  const int nbx = gridDim.x;
  const int nwg = nbx * gridDim.y;
  const int orig = blockIdx.y * nbx + blockIdx.x;
  const int qq = nwg >> 3, rr = nwg & 7;
  const int xc = orig & 7, kk = orig >> 3;
  const int wg = (xc < rr ? xc * (qq + 1) : rr * (qq + 1) + (xc - rr) * qq) + kk;
  const int n0 = (wg % nbx) * 128;
  const int m0 = (wg / nbx) * 128;

  const int lane = t & 63, w = t >> 6;
  const int wm = (w & 1) * 64, wn = (w >> 1) * 64;
  const int q = lane >> 4, r16 = lane & 15;

  const bf16_t* As[4] = {A0, A1, A2, A3};
  const bf16_t* Bs[4] = {B0, B1, B2, B3};
  const float* biasp = bias;
  int half = 0;
  int of32 = 0;
  if (EPI == 1) {
    of32 = *oflag;
    half = blockIdx.z;
    if (half) { As[0] = A1; Bs[0] = B1; }
    biasp = bias + half * FD;
  }

  f32x4 acc[4][4];
#pragma unroll
  for (int i = 0; i < 4; ++i)
#pragma unroll
    for (int j = 0; j < 4; ++j) acc[i][j] = (f32x4){0.f, 0.f, 0.f, 0.f};

  // staging geometry: wave w fills rows [w*32, w*32+32); lane l -> row w*32+l/4,
  // 16B chunk (l%4). glds dest is wave-uniform base + lane*16B.
  const int srow = w * 32 + (lane >> 2);
  const int schunk = (lane & 3) * 8;
  const int so = (w * 32) * 32;
  const int so16 = (w * 32 + 16) * 32;

  auto stage = [&](const bf16_t* ga, const bf16_t* gb, short* la, short* lb) {
    glds16(ga, la + so);
    glds16(ga + (size_t)16 * FD, la + so16);
    glds16(gb, lb + so);
    glds16(gb + (size_t)16 * FD, lb + so16);
  };
  auto compute = [&](const short* bA, const short* bB) {
    short8 af[4], bfr[4];
#pragma unroll
    for (int i = 0; i < 4; ++i) {
      af[i] = *(const short8*)(bA + (wm + i * 16 + r16) * 32 + q * 8);
      bfr[i] = *(const short8*)(bB + (wn + i * 16 + r16) * 32 + q * 8);
    }
#pragma unroll
    for (int i = 0; i < 4; ++i)
#pragma unroll
      for (int j = 0; j < 4; ++j)
        acc[i][j] = __builtin_amdgcn_mfma_f32_16x16x32_bf16(af[i], bfr[j], acc[i][j], 0, 0, 0);
  };

  // prologue: stage tile (0,0) into buf0
  const bf16_t* pa = As[0] + (size_t)(m0 + srow) * FD + schunk;
  const bf16_t* pb = Bs[0] + (size_t)(n0 + srow) * FD + schunk;
  stage(pa, pb, sA0, sB0);
  __syncthreads();

#pragma unroll
  for (int seg = 0; seg < NSEG; ++seg) {
#pragma unroll 1
    for (int kb2 = 0; kb2 < 8; ++kb2) {
      // even tile 2*kb2 in buf0: stage odd tile 2*kb2+1 into buf1, then compute
      stage(pa + 32, pb + 32, sA1, sB1);
      compute(sA0, sB0);
      __syncthreads();  // implicit vmcnt(0): buf1 landed; all reads of buf0 done
      // odd tile in buf1: stage next even tile (this seg, next seg, or none)
      const bf16_t* qa;
      const bf16_t* qb;
      bool have = true;
      if (kb2 < 7) {
        qa = pa + 64;
        qb = pb + 64;
      } else if (seg + 1 < NSEG) {
        qa = As[seg + 1] + (size_t)(m0 + srow) * FD + schunk;
        qb = Bs[seg + 1] + (size_t)(n0 + srow) * FD + schunk;
      } else {
        qa = pa;
        qb = pb;
        have = false;
      }
      if (have) stage(qa, qb, sA0, sB0);
      compute(sA1, sB1);
      __syncthreads();
      pa = qa;
      pb = qb;
    }
  }

  float bcol[4];
#pragma unroll
  for (int j = 0; j < 4; ++j) bcol[j] = biasp[n0 + wn + j * 16 + r16];

  if (EPI == 0) {
    bf16_t* Cb = (bf16_t*)Cout;
    float ps[4] = {0.f, 0.f, 0.f, 0.f}, pq[4] = {0.f, 0.f, 0.f, 0.f};
#pragma unroll
    for (int i = 0; i < 4; ++i) {
#pragma unroll
      for (int rg = 0; rg < 4; ++rg) {
        int gr = m0 + wm + i * 16 + q * 4 + rg;  // C/D: col=lane&15, row=(lane>>4)*4+reg
        if (gr >= M) continue;
#pragma unroll
        for (int j = 0; j < 4; ++j) {
          int col = n0 + wn + j * 16 + r16;
          bf16_t rb = __float2bfloat16(acc[i][j][rg] + bcol[j]);
          Cb[(size_t)gr * FD + col] = rb;
          float xr = __bfloat162float(rb);  // stats of the stored (rounded) tensor
          ps[j] += xr;
          pq[j] += xr * xr;
        }
      }
    }
#pragma unroll
    for (int j = 0; j < 4; ++j) {
      float s = ps[j], qq2 = pq[j];
      s += __shfl_xor(s, 16);
      s += __shfl_xor(s, 32);
      qq2 += __shfl_xor(qq2, 16);
      qq2 += __shfl_xor(qq2, 32);
      if (q == 0) {
        int col = n0 + wn + j * 16 + r16;
        atomicAdd(&stats[col], s);
        atomicAdd(&stats[FD + col], qq2);
      }
    }
  } else {
    float* outf = (float*)Cout + (size_t)half * M * FD;
    bf16_t* outb = (bf16_t*)Cout + (size_t)half * M * FD;
#pragma unroll
    for (int i = 0; i < 4; ++i) {
#pragma unroll
      for (int rg = 0; rg < 4; ++rg) {
        int gr = m0 + wm + i * 16 + q * 4 + rg;
        if (gr >= M) continue;
#pragma unroll
        for (int j = 0; j < 4; ++j) {
          int col = n0 + wn + j * 16 + r16;
          float y = acc[i][j][rg] + bcol[j];
          if (of32)
            outf[(size_t)gr * FD + col] = y;
          else
            outb[(size_t)gr * FD + col] = __float2bfloat16(y);
        }
      }
    }
  }
}

// ---------------- BN finalize (per-block, fused) + apply ----------------
// Each block recomputes the 512 scale/shift pairs into LDS (~0.5us of redundant
// rsqrt) -- removes the serialized 1-block bn_fin dispatch between GEMM and apply.
__global__ void bn_apply_k(const bf16_t* __restrict__ x, const float* __restrict__ stats,
                           const void* gamma, const void* beta, unsigned long long goff,
                           float Mf, bf16_t* __restrict__ out, int total8, const int* flag) {
  __shared__ float scsh[2 * FD];
  int f = *flag;
  for (int c = threadIdx.x; c < FD; c += 256) {
    float m = stats[c] / Mf;
    float v = fmaxf(stats[FD + c] / Mf - m * m, 0.f);
    float sc = ldf(gamma, goff + c, f) * rsqrtf(v + 1e-5f);
    scsh[c] = sc;
    scsh[FD + c] = ldf(beta, goff + c, f) - m * sc;
  }
  __syncthreads();
  int p = blockIdx.x * 256 + threadIdx.x;
  if (p >= total8) return;
  int e = p * 8;
  int col = e & (FD - 1);
  uint4 u = *(const uint4*)(x + e);
  bf162_t* pr = (bf162_t*)&u;
  uint4 ov;
  bf162_t* po = (bf162_t*)&ov;
#pragma unroll
  for (int i = 0; i < 4; ++i) {
    float x0 = __bfloat162float(pr[i].x) * scsh[col + 2 * i] + scsh[FD + col + 2 * i];
    float x1 = __bfloat162float(pr[i].y) * scsh[col + 2 * i + 1] + scsh[FD + col + 2 * i + 1];
    po[i].x = __float2bfloat16(fmaxf(0.f, x0));
    po[i].y = __float2bfloat16(fmaxf(0.f, x1));
  }
  *(uint4*)(out + e) = ov;
}

// ---------------- host orchestration ----------------
extern "C" void kernel_launch(void* const* d_in, const int* in_sizes, int n_in,
                              void* d_out, int out_size, void* d_ws, size_t ws_size,
                              hipStream_t stream) {
  const int Mn = in_sizes[0] / FD;          // 20000
  const int Mp = (Mn + 127) & ~127;         // 20096
  const int E = in_sizes[14];               // 320000
  const size_t SZ = (size_t)FD * FD;

  const void* hd_raw = d_in[0];
  const void* hp_raw = d_in[1];
  const void* Ws1 = d_in[2];
  const void* Wn1 = d_in[3];
  const void* b1 = d_in[4];
  const void* Ws2 = d_in[5];
  const void* Wn2 = d_in[6];
  const void* b2 = d_in[7];
  const void* bng = d_in[8];
  const void* bnb = d_in[9];
  const void* pWd = d_in[10];
  const void* pbd = d_in[11];
  const void* pWp = d_in[12];
  const void* pbp = d_in[13];
  const int* a_src = (const int*)d_in[14];
  const int* a_dst = (const int*)d_in[15];
  const int* i_src = (const int*)d_in[16];
  const int* i_dst = (const int*)d_in[17];

  char* wptr = (char*)d_ws;
  auto alloc = [&](size_t bytes) {
    char* p = wptr;
    wptr += (bytes + 255) & ~(size_t)255;
    return p;
  };
  bf16_t* Bt = (bf16_t*)alloc(14 * SZ * 2);
  float* biasf = (float*)alloc(6 * FD * 4);
  float* stats = (float*)alloc(4 * FD * 4);  // [sum_d|sq_d|sum_p|sq_p]
  int* dtflag = (int*)alloc(256);
  int* deg = (int*)alloc((size_t)4 * Mn * 4);
  int* offs = (int*)alloc((size_t)4 * (Mn + 1) * 4);
  int* curs = (int*)alloc((size_t)4 * Mn * 4);
  int* evals = (int*)alloc((size_t)4 * E * 4);
  bf16_t* accb = (bf16_t*)alloc((size_t)Mp * FD * 2);  // bf16 pre-BN tensor (shared d/p)
  bf16_t* h_d = (bf16_t*)alloc((size_t)Mp * FD * 2);
  bf16_t* h_p = (bf16_t*)alloc((size_t)Mp * FD * 2);
  bf16_t* mean0 = (bf16_t*)alloc((size_t)Mp * FD * 2);
  bf16_t* mean1 = (bf16_t*)alloc((size_t)Mp * FD * 2);
  bf16_t* mean2 = (bf16_t*)alloc((size_t)Mp * FD * 2);
  bf16_t* mean3 = (bf16_t*)alloc((size_t)Mp * FD * 2);

  detect_k<<<1, 256, 0, stream>>>((const unsigned int*)hd_raw, 4096, dtflag);
  const int nh = Mn * FD, nhp = Mp * FD;
  conv_h_k<<<dim3((nhp / 4 + 255) / 256, 2), 256, 0, stream>>>(hd_raw, hp_raw, h_d, h_p, nh, nhp,
                                                               dtflag);

  hipMemsetAsync(deg, 0, (size_t)4 * Mn * 4, stream);
  int eb = (E + 255) / 256;
  count_deg_k<<<eb, 256, 0, stream>>>(a_src, a_dst, i_src, i_dst, deg, Mn, E);
  scan_k<<<4, 256, 0, stream>>>(deg, offs, curs, Mn);
  fill_k<<<dim3(eb, 4), 256, 0, stream>>>(a_src, a_dst, i_src, i_dst, curs, evals, Mn, E);

  // Bt slots: [0..3]=Wn1T[r], [4..7]=Wn2T[r], [8]=Ws1(0+2+3)T, [9]=Ws1(1)T,
  //           [10]=Ws2(0+2+3)T, [11]=Ws2(1)T, [12]=projWdT, [13]=projWpT
  TSlots ts;
  for (int z = 0; z < 14; ++z) { ts.s1[z] = -1; ts.s2[z] = -1; ts.o1[z] = 0; ts.o2[z] = 0; }
  for (int r = 0; r < 4; ++r) { ts.s0[r] = 1; ts.o0[r] = (unsigned long long)r * SZ; }
  for (int r = 0; r < 4; ++r) { ts.s0[4 + r] = 3; ts.o0[4 + r] = (unsigned long long)r * SZ; }
  ts.s0[8] = 0; ts.o0[8] = 0; ts.s1[8] = 0; ts.o1[8] = 2 * SZ; ts.s2[8] = 0; ts.o2[8] = 3 * SZ;
  ts.s0[9] = 0; ts.o0[9] = 1 * SZ;
  ts.s0[10] = 2; ts.o0[10] = 0; ts.s1[10] = 2; ts.o1[10] = 2 * SZ; ts.s2[10] = 2; ts.o2[10] = 3 * SZ;
  ts.s0[11] = 2; ts.o0[11] = 1 * SZ;
  ts.s0[12] = 4; ts.o0[12] = 0;
  ts.s0[13] = 5; ts.o0[13] = 0;
  transpose_all_k<<<dim3(16, 16, 14), dim3(32, 8), 0, stream>>>(Ws1, Wn1, Ws2, Wn2, pWd, pWp,
                                                                ts, Bt, dtflag);
  prep_bias_k<<<1, 256, 0, stream>>>(b1, b2, pbd, pbp, biasf, dtflag);

  dim3 ggrid(4, Mp / 128);
  dim3 sgrid(Mp / 32, 32);  // x = node-group (32 nodes/block), y = (rel,slice) pass
  const int bn8 = (Mn * FD / 8 + 255) / 256;

  auto layer = [&](int wn0, int wsp, int wsd, const float* bd, const float* bp,
                   unsigned long long goff_d, unsigned long long goff_p) {
    seg_mean_g8_k<<<sgrid, 256, 0, stream>>>(h_d, h_p, offs, evals, Mn, E, mean0, mean1,
                                             mean2, mean3);
    hipMemsetAsync(stats, 0, 4 * FD * 4, stream);
    // disease = hd@Ws[1] + mean1@Wn[1] + b   (K-concat, 2 segments)
    gemm_f<2, 0><<<ggrid, 256, 0, stream>>>(h_d, mean1, nullptr, nullptr,
                                            Bt + (size_t)wsd * SZ, Bt + (size_t)(wn0 + 1) * SZ,
                                            nullptr, nullptr, bd, accb, stats, Mn, dtflag);
    bn_apply_k<<<bn8, 256, 0, stream>>>(accb, stats, bng, bnb, goff_d, (float)Mn, h_d,
                                        Mn * FD / 8, dtflag);
    // protein = hp@(Ws0+Ws2+Ws3) + mean0@Wn0 + mean2@Wn2 + mean3@Wn3 + b   (4 segments)
    gemm_f<4, 0><<<ggrid, 256, 0, stream>>>(h_p, mean0, mean2, mean3,
                                            Bt + (size_t)wsp * SZ, Bt + (size_t)(wn0 + 0) * SZ,
                                            Bt + (size_t)(wn0 + 2) * SZ,
                                            Bt + (size_t)(wn0 + 3) * SZ, bp, accb,
                                            stats + 2 * FD, Mn, dtflag);
    bn_apply_k<<<bn8, 256, 0, stream>>>(accb, stats + 2 * FD, bng, bnb, goff_p, (float)Mn, h_p,
                                        Mn * FD / 8, dtflag);
  };

  // bn params layout [layer][ntype][512], ntype 0=disease 1=protein
  layer(0, 8, 9, biasf + 0 * FD, biasf + 1 * FD, 0ULL * FD, 1ULL * FD);
  layer(4, 10, 11, biasf + 2 * FD, biasf + 3 * FD, 2ULL * FD, 3ULL * FD);

  // merged final projections -> d_out (z=0: disease half, z=1: protein half)
  gemm_f<1, 1><<<dim3(4, Mp / 128, 2), 256, 0, stream>>>(
      h_d, h_p, nullptr, nullptr, Bt + 12 * SZ, Bt + 13 * SZ, nullptr, nullptr,
      biasf + 4 * FD, d_out, nullptr, Mn, dtflag);
}

// Round 5
// 816.844 us; speedup vs baseline: 1.3960x; 1.0703x over previous
//
#include <hip/hip_runtime.h>
#include <hip/hip_bf16.h>

typedef __attribute__((ext_vector_type(8))) short short8;
typedef __attribute__((ext_vector_type(4))) float f32x4;
using bf16_t = __hip_bfloat16;
using bf162_t = __hip_bfloat162;

#define FD 512

__device__ __forceinline__ float ldf(const void* p, size_t i, int f32) {
  return f32 ? ((const float*)p)[i] : __bfloat162float(((const bf16_t*)p)[i]);
}

// CK-pattern async global->LDS, 16B per lane (global_load_lds_dwordx4)
__device__ __forceinline__ void glds16(const bf16_t* g, short* l) {
  __builtin_amdgcn_global_load_lds(
      (const __attribute__((address_space(1))) unsigned int*)g,
      (__attribute__((address_space(3))) unsigned int*)(uintptr_t)l, 16, 0, 0);
}

// ---------------- dtype detect (fp32 vs bf16 device tensors) ----------------
__global__ void detect_k(const unsigned int* w, int nwords, int* flag) {
  __shared__ int cnt_s;
  if (threadIdx.x == 0) cnt_s = 0;
  __syncthreads();
  int c = 0;
  for (int i = threadIdx.x; i < nwords; i += 256) {
    unsigned lo = w[i] & 0xFFFFu;
    unsigned ex = (lo >> 7) & 0xFFu;
    if (lo == 0u || (ex >= 100u && ex <= 140u)) c++;
  }
  atomicAdd(&cnt_s, c);
  __syncthreads();
  if (threadIdx.x == 0) *flag = (2 * cnt_s < nwords) ? 1 : 0;
}

// convert h (z=0: disease, z=1: protein) to canonical bf16, zero pad rows
__global__ void conv_h_k(const void* s0, const void* s1, bf16_t* d0, bf16_t* d1, int n, int npad,
                         const int* flag) {
  int f = *flag;
  const void* src = blockIdx.y ? s1 : s0;
  bf16_t* dst = blockIdx.y ? d1 : d0;
  int e = (blockIdx.x * 256 + threadIdx.x) * 4;
  if (e >= npad) return;
  bf162_t o0, o1;
  if (e + 3 < n) {
    o0.x = __float2bfloat16(ldf(src, e + 0, f));
    o0.y = __float2bfloat16(ldf(src, e + 1, f));
    o1.x = __float2bfloat16(ldf(src, e + 2, f));
    o1.y = __float2bfloat16(ldf(src, e + 3, f));
  } else {
    float v[4];
    for (int u = 0; u < 4; ++u) v[u] = (e + u < n) ? ldf(src, e + u, f) : 0.f;
    o0.x = __float2bfloat16(v[0]); o0.y = __float2bfloat16(v[1]);
    o1.x = __float2bfloat16(v[2]); o1.y = __float2bfloat16(v[3]);
  }
  *(bf162_t*)(dst + e) = o0;
  *(bf162_t*)(dst + e + 2) = o1;
}

// ---------------- CSR build ----------------
__global__ void count_deg_k(const int* __restrict__ a_src, const int* __restrict__ a_dst,
                            const int* __restrict__ i_src, const int* __restrict__ i_dst,
                            int* __restrict__ deg, int M, int E) {
  int e = blockIdx.x * 256 + threadIdx.x;
  if (e >= E) return;
  atomicAdd(&deg[0 * M + a_dst[e]], 1);
  atomicAdd(&deg[1 * M + a_src[e]], 1);
  atomicAdd(&deg[2 * M + i_dst[e]], 1);
  atomicAdd(&deg[3 * M + i_src[e]], 1);
}

__global__ void scan_k(const int* __restrict__ deg, int* __restrict__ offs,
                       int* __restrict__ curs, int n) {
  const int r = blockIdx.x;
  const int* d = deg + r * n;
  int* off = offs + r * (n + 1);
  int* cur = curs + r * n;
  __shared__ int part[256];
  const int t = threadIdx.x;
  const int chunk = (n + 255) / 256;
  const int s0 = t * chunk;
  const int s1 = min(n, s0 + chunk);
  int sum = 0;
  for (int i = s0; i < s1; ++i) sum += d[i];
  part[t] = sum;
  __syncthreads();
  if (t == 0) {
    int run = 0;
    for (int i = 0; i < 256; ++i) { int v = part[i]; part[i] = run; run += v; }
  }
  __syncthreads();
  int run = part[t];
  for (int i = s0; i < s1; ++i) { off[i] = run; cur[i] = run; run += d[i]; }
  if (t == 255) off[n] = run;
}

__global__ void fill_k(const int* __restrict__ a_src, const int* __restrict__ a_dst,
                       const int* __restrict__ i_src, const int* __restrict__ i_dst,
                       int* __restrict__ curs, int* __restrict__ evals, int M, int E) {
  int r = blockIdx.y;
  int e = blockIdx.x * 256 + threadIdx.x;
  if (e >= E) return;
  const int* dsts[4] = {a_dst, a_src, i_dst, i_src};
  const int* vals[4] = {a_src, a_dst, i_src, i_dst};
  int d = dsts[r][e];
  int pos = atomicAdd(&curs[r * M + d], 1);
  evals[r * E + pos] = vals[r][e];
}

// ---------------- feature-sliced fused segment mean, 8-lane node groups ----------------
// 8 slices of 64 feats: (table, slice) working set = 2.56 MB -> L2-resident per XCD.
// 8 lanes/node x 16B = 128B row-slice; a wave gathers 8 nodes = 1KB per instruction.
// NEW (r5): XCD pass-affinity swizzle -- flat-id bijective chunk swizzle gives each
// XCD 4 consecutive (rel,slice) passes, so a slice is fetched into ONE XCD L2
// instead of duplicated across all 8 (round-4 FETCH 211 MB, prediction ~100 MB).
__global__ void seg_mean_g8_k(const bf16_t* __restrict__ hd, const bf16_t* __restrict__ hp,
                              const int* __restrict__ offs, const int* __restrict__ evals,
                              int Mn, int E,
                              bf16_t* __restrict__ m0b, bf16_t* __restrict__ m1b,
                              bf16_t* __restrict__ m2b, bf16_t* __restrict__ m3b) {
  const int gx = gridDim.x;
  const int nwg = gx * gridDim.y;           // 628*32 = 20096, divisible by 8
  int flat = blockIdx.y * gx + blockIdx.x;
  const int cpx = nwg >> 3;
  flat = (flat & 7) * cpx + (flat >> 3);    // XCD (orig%8) owns contiguous pass chunk
  const int y = flat / gx;
  const int nodeblk = flat % gx;

  int rel, sl;
  if (y < 24) { rel = 1 + y % 3; sl = y / 3; }
  else        { rel = 0;         sl = y - 24; }
  const bf16_t* __restrict__ h = (rel == 0) ? hd : hp;
  bf16_t* mb = (rel == 0) ? m0b : (rel == 1) ? m1b : (rel == 2) ? m2b : m3b;

  const int t = threadIdx.x;
  const int g = t >> 3, sub = t & 7;       // 32 node-groups per block, 8 lanes each
  const int node = nodeblk * 32 + g;       // grid.x = Mp/32; pad nodes write zeros
  int s = 0, e = 0;
  if (node < Mn) {
    const int* off = offs + rel * (Mn + 1) + node;
    s = off[0];
    e = off[1];
  }
  const int* __restrict__ ev = evals + (size_t)rel * E;
  const bf16_t* hs = h + sl * 64 + sub * 8;  // 16B per lane within the 128B slice

  float a[8] = {0.f, 0.f, 0.f, 0.f, 0.f, 0.f, 0.f, 0.f};
  int c = s;
  for (; c + 3 < e; c += 4) {  // 4 independent 1KB wave-gathers in flight
    int n0 = ev[c], n1 = ev[c + 1], n2 = ev[c + 2], n3 = ev[c + 3];
    uint4 u0 = *(const uint4*)(hs + (size_t)n0 * FD);
    uint4 u1 = *(const uint4*)(hs + (size_t)n1 * FD);
    uint4 u2 = *(const uint4*)(hs + (size_t)n2 * FD);
    uint4 u3 = *(const uint4*)(hs + (size_t)n3 * FD);
    bf162_t* p0 = (bf162_t*)&u0;
    bf162_t* p1 = (bf162_t*)&u1;
    bf162_t* p2 = (bf162_t*)&u2;
    bf162_t* p3 = (bf162_t*)&u3;
#pragma unroll
    for (int i = 0; i < 4; ++i) {
      a[2 * i] += __bfloat162float(p0[i].x) + __bfloat162float(p1[i].x) +
                  __bfloat162float(p2[i].x) + __bfloat162float(p3[i].x);
      a[2 * i + 1] += __bfloat162float(p0[i].y) + __bfloat162float(p1[i].y) +
                      __bfloat162float(p2[i].y) + __bfloat162float(p3[i].y);
    }
  }
  for (; c < e; ++c) {
    uint4 u = *(const uint4*)(hs + (size_t)ev[c] * FD);
    bf162_t* pr = (bf162_t*)&u;
#pragma unroll
    for (int i = 0; i < 4; ++i) {
      a[2 * i] += __bfloat162float(pr[i].x);
      a[2 * i + 1] += __bfloat162float(pr[i].y);
    }
  }
  float inv = (e > s) ? 1.f / (float)(e - s) : 0.f;
  uint4 ov;
  bf162_t* po = (bf162_t*)&ov;
#pragma unroll
  for (int i = 0; i < 4; ++i) {
    po[i].x = __float2bfloat16(a[2 * i] * inv);
    po[i].y = __float2bfloat16(a[2 * i + 1] * inv);
  }
  *(uint4*)(mb + (size_t)node * FD + sl * 64 + sub * 8) = ov;  // 128B/group coalesced
}

// ---------------- fused weight transpose: dst[n][k] = sum of up to 3 W[k][n] ----------------
struct TSlots {
  int s0[14], s1[14], s2[14];
  unsigned long long o0[14], o1[14], o2[14];
};

__global__ void transpose_all_k(const void* p0, const void* p1, const void* p2, const void* p3,
                                const void* p4, const void* p5, TSlots ts,
                                bf16_t* __restrict__ BtAll, const int* flag) {
  int f = *flag;
  const void* bases[6] = {p0, p1, p2, p3, p4, p5};
  const int z = blockIdx.z;
  const void* s0 = bases[ts.s0[z]];
  const void* s1 = (ts.s1[z] >= 0) ? bases[ts.s1[z]] : nullptr;
  const void* s2 = (ts.s2[z] >= 0) ? bases[ts.s2[z]] : nullptr;
  const unsigned long long o0 = ts.o0[z], o1 = ts.o1[z], o2 = ts.o2[z];
  bf16_t* dst = BtAll + (size_t)z * FD * FD;
  __shared__ float tile[32][33];
  const int nb = blockIdx.x * 32;
  const int kb = blockIdx.y * 32;
  const int tx = threadIdx.x, ty = threadIdx.y;
  for (int j = 0; j < 32; j += 8) {
    size_t k = kb + ty + j, n = nb + tx;
    float v = ldf(s0, o0 + k * FD + n, f);
    if (s1) v += ldf(s1, o1 + k * FD + n, f);
    if (s2) v += ldf(s2, o2 + k * FD + n, f);
    tile[ty + j][tx] = v;
  }
  __syncthreads();
  for (int j = 0; j < 32; j += 8)
    dst[(size_t)(nb + ty + j) * FD + kb + tx] = __float2bfloat16(tile[tx][ty + j]);
}

__global__ void prep_bias_k(const void* b1, const void* b2, const void* pbd, const void* pbp,
                            float* __restrict__ out, const int* flag) {
  int f = *flag;
  for (int c = threadIdx.x; c < FD; c += 256) {
    out[0 * FD + c] = ldf(b1, 1 * FD + c, f);
    out[1 * FD + c] = ldf(b1, 0 * FD + c, f) + ldf(b1, 2 * FD + c, f) + ldf(b1, 3 * FD + c, f);
    out[2 * FD + c] = ldf(b2, 1 * FD + c, f);
    out[3 * FD + c] = ldf(b2, 0 * FD + c, f) + ldf(b2, 2 * FD + c, f) + ldf(b2, 3 * FD + c, f);
    out[4 * FD + c] = ldf(pbd, c, f);
    out[5 * FD + c] = ldf(pbp, c, f);
  }
}

// ---------------- multi-segment fused GEMM core, 2-phase LDS double-buffer ----------------
// C[M,512] = sum_s A_s[Mpad,512] @ B_s[512,512]^T(stored [n][k]) + bias
// 2-phase (T3-min): stage tile t+1 before computing tile t; one barrier per k-step.
// EPI 0: bf16 C + fused BN column stats; EPI 1: output store (dtype by of32, half offset).
// XCD-bijective tile swizzle (m204) for A-panel L2 locality.
template <int NSEG, int EPI>
__device__ __forceinline__ void gemm_core(
    const bf16_t* __restrict__ A0, const bf16_t* __restrict__ A1,
    const bf16_t* __restrict__ A2, const bf16_t* __restrict__ A3,
    const bf16_t* __restrict__ B0, const bf16_t* __restrict__ B1,
    const bf16_t* __restrict__ B2, const bf16_t* __restrict__ B3,
    const float* __restrict__ biasp, void* __restrict__ Cout,
    float* __restrict__ stats, int M, int of32, int half,
    short* sA0, short* sB0, short* sA1, short* sB1) {
  const int t = threadIdx.x;

  const int nbx = gridDim.x;
  const int nwg = nbx * gridDim.y;
  const int orig = blockIdx.y * nbx + blockIdx.x;
  const int qq = nwg >> 3, rr = nwg & 7;
  const int xc = orig & 7, kk = orig >> 3;
  const int wg = (xc < rr ? xc * (qq + 1) : rr * (qq + 1) + (xc - rr) * qq) + kk;
  const int n0 = (wg % nbx) * 128;
  const int m0 = (wg / nbx) * 128;

  const int lane = t & 63, w = t >> 6;
  const int wm = (w & 1) * 64, wn = (w >> 1) * 64;
  const int q = lane >> 4, r16 = lane & 15;

  const bf16_t* As[4] = {A0, A1, A2, A3};
  const bf16_t* Bs[4] = {B0, B1, B2, B3};

  f32x4 acc[4][4];
#pragma unroll
  for (int i = 0; i < 4; ++i)
#pragma unroll
    for (int j = 0; j < 4; ++j) acc[i][j] = (f32x4){0.f, 0.f, 0.f, 0.f};

  // staging geometry: wave w fills rows [w*32, w*32+32); lane l -> row w*32+l/4,
  // 16B chunk (l%4). glds dest is wave-uniform base + lane*16B.
  const int srow = w * 32 + (lane >> 2);
  const int schunk = (lane & 3) * 8;
  const int so = (w * 32) * 32;
  const int so16 = (w * 32 + 16) * 32;

  auto stage = [&](const bf16_t* ga, const bf16_t* gb, short* la, short* lb) {
    glds16(ga, la + so);
    glds16(ga + (size_t)16 * FD, la + so16);
    glds16(gb, lb + so);
    glds16(gb + (size_t)16 * FD, lb + so16);
  };
  auto compute = [&](const short* bA, const short* bB) {
    short8 af[4], bfr[4];
#pragma unroll
    for (int i = 0; i < 4; ++i) {
      af[i] = *(const short8*)(bA + (wm + i * 16 + r16) * 32 + q * 8);
      bfr[i] = *(const short8*)(bB + (wn + i * 16 + r16) * 32 + q * 8);
    }
#pragma unroll
    for (int i = 0; i < 4; ++i)
#pragma unroll
      for (int j = 0; j < 4; ++j)
        acc[i][j] = __builtin_amdgcn_mfma_f32_16x16x32_bf16(af[i], bfr[j], acc[i][j], 0, 0, 0);
  };

  // prologue: stage tile (0,0) into buf0
  const bf16_t* pa = As[0] + (size_t)(m0 + srow) * FD + schunk;
  const bf16_t* pb = Bs[0] + (size_t)(n0 + srow) * FD + schunk;
  stage(pa, pb, sA0, sB0);
  __syncthreads();

#pragma unroll
  for (int seg = 0; seg < NSEG; ++seg) {
#pragma unroll 1
    for (int kb2 = 0; kb2 < 8; ++kb2) {
      // even tile 2*kb2 in buf0: stage odd tile 2*kb2+1 into buf1, then compute
      stage(pa + 32, pb + 32, sA1, sB1);
      compute(sA0, sB0);
      __syncthreads();  // implicit vmcnt(0): buf1 landed; all reads of buf0 done
      // odd tile in buf1: stage next even tile (this seg, next seg, or none)
      const bf16_t* qa;
      const bf16_t* qb;
      bool have = true;
      if (kb2 < 7) {
        qa = pa + 64;
        qb = pb + 64;
      } else if (seg + 1 < NSEG) {
        qa = As[seg + 1] + (size_t)(m0 + srow) * FD + schunk;
        qb = Bs[seg + 1] + (size_t)(n0 + srow) * FD + schunk;
      } else {
        qa = pa;
        qb = pb;
        have = false;
      }
      if (have) stage(qa, qb, sA0, sB0);
      compute(sA1, sB1);
      __syncthreads();
      pa = qa;
      pb = qb;
    }
  }

  float bcol[4];
#pragma unroll
  for (int j = 0; j < 4; ++j) bcol[j] = biasp[n0 + wn + j * 16 + r16];

  if (EPI == 0) {
    bf16_t* Cb = (bf16_t*)Cout;
    float ps[4] = {0.f, 0.f, 0.f, 0.f}, pq[4] = {0.f, 0.f, 0.f, 0.f};
#pragma unroll
    for (int i = 0; i < 4; ++i) {
#pragma unroll
      for (int rg = 0; rg < 4; ++rg) {
        int gr = m0 + wm + i * 16 + q * 4 + rg;  // C/D: col=lane&15, row=(lane>>4)*4+reg
        if (gr >= M) continue;
#pragma unroll
        for (int j = 0; j < 4; ++j) {
          int col = n0 + wn + j * 16 + r16;
          bf16_t rb = __float2bfloat16(acc[i][j][rg] + bcol[j]);
          Cb[(size_t)gr * FD + col] = rb;
          float xr = __bfloat162float(rb);  // stats of the stored (rounded) tensor
          ps[j] += xr;
          pq[j] += xr * xr;
        }
      }
    }
#pragma unroll
    for (int j = 0; j < 4; ++j) {
      float s = ps[j], qq2 = pq[j];
      s += __shfl_xor(s, 16);
      s += __shfl_xor(s, 32);
      qq2 += __shfl_xor(qq2, 16);
      qq2 += __shfl_xor(qq2, 32);
      if (q == 0) {
        int col = n0 + wn + j * 16 + r16;
        atomicAdd(&stats[col], s);
        atomicAdd(&stats[FD + col], qq2);
      }
    }
  } else {
    float* outf = (float*)Cout + (size_t)half * M * FD;
    bf16_t* outb = (bf16_t*)Cout + (size_t)half * M * FD;
#pragma unroll
    for (int i = 0; i < 4; ++i) {
#pragma unroll
      for (int rg = 0; rg < 4; ++rg) {
        int gr = m0 + wm + i * 16 + q * 4 + rg;
        if (gr >= M) continue;
#pragma unroll
        for (int j = 0; j < 4; ++j) {
          int col = n0 + wn + j * 16 + r16;
          float y = acc[i][j][rg] + bcol[j];
          if (of32)
            outf[(size_t)gr * FD + col] = y;
          else
            outb[(size_t)gr * FD + col] = __float2bfloat16(y);
        }
      }
    }
  }
}

// One dispatch per layer: z=0 disease GEMM (NSEG=2), z=1 protein GEMM (NSEG=4).
// Independent outputs (accd/accp) and disjoint stats sections -> safe concurrency;
// fills the machine (1256 blocks) and overlaps the two GEMMs' tails.
__global__ __launch_bounds__(256) void gemm_layer_k(
    const bf16_t* __restrict__ hd, const bf16_t* __restrict__ m1,
    const bf16_t* __restrict__ Bd0, const bf16_t* __restrict__ Bd1,
    const bf16_t* __restrict__ hp, const bf16_t* __restrict__ m0,
    const bf16_t* __restrict__ m2, const bf16_t* __restrict__ m3,
    const bf16_t* __restrict__ Bp0, const bf16_t* __restrict__ Bp1,
    const bf16_t* __restrict__ Bp2, const bf16_t* __restrict__ Bp3,
    const float* __restrict__ bd, const float* __restrict__ bp,
    bf16_t* __restrict__ accd, bf16_t* __restrict__ accp,
    float* __restrict__ stats, int M) {
  __shared__ __align__(16) short sA0[128 * 32];
  __shared__ __align__(16) short sB0[128 * 32];
  __shared__ __align__(16) short sA1[128 * 32];
  __shared__ __align__(16) short sB1[128 * 32];
  if (blockIdx.z == 0)
    gemm_core<2, 0>(hd, m1, nullptr, nullptr, Bd0, Bd1, nullptr, nullptr,
                    bd, accd, stats, M, 0, 0, sA0, sB0, sA1, sB1);
  else
    gemm_core<4, 0>(hp, m0, m2, m3, Bp0, Bp1, Bp2, Bp3,
                    bp, accp, stats + 2 * FD, M, 0, 0, sA0, sB0, sA1, sB1);
}

// merged final projections: z=0 disease half, z=1 protein half
__global__ __launch_bounds__(256) void gemm_final_k(
    const bf16_t* __restrict__ hd, const bf16_t* __restrict__ hp,
    const bf16_t* __restrict__ Bd, const bf16_t* __restrict__ Bp,
    const float* __restrict__ bias, void* __restrict__ out, int M, const int* oflag) {
  __shared__ __align__(16) short sA0[128 * 32];
  __shared__ __align__(16) short sB0[128 * 32];
  __shared__ __align__(16) short sA1[128 * 32];
  __shared__ __align__(16) short sB1[128 * 32];
  const int of32 = *oflag;
  if (blockIdx.z == 0)
    gemm_core<1, 1>(hd, nullptr, nullptr, nullptr, Bd, nullptr, nullptr, nullptr,
                    bias, out, nullptr, M, of32, 0, sA0, sB0, sA1, sB1);
  else
    gemm_core<1, 1>(hp, nullptr, nullptr, nullptr, Bp, nullptr, nullptr, nullptr,
                    bias + FD, out, nullptr, M, of32, 1, sA0, sB0, sA1, sB1);
}

// ---------------- BN finalize (per-block, fused) + apply, both ntypes ----------------
// y=0: disease (accd -> h_d), y=1: protein (accp -> h_p). Each block recomputes the
// 512 scale/shift pairs into LDS; removes serialized bn_fin dispatches.
__global__ void bn2_apply_k(const bf16_t* __restrict__ xd, const bf16_t* __restrict__ xp,
                            const float* __restrict__ stats, const void* gamma,
                            const void* beta, unsigned long long goff_d,
                            unsigned long long goff_p, float Mf,
                            bf16_t* __restrict__ outd, bf16_t* __restrict__ outp,
                            int total8, const int* flag) {
  __shared__ float scsh[2 * FD];
  const int half = blockIdx.y;
  const bf16_t* __restrict__ x = half ? xp : xd;
  bf16_t* __restrict__ out = half ? outp : outd;
  const float* __restrict__ st = stats + (half ? 2 * FD : 0);
  const unsigned long long goff = half ? goff_p : goff_d;
  int f = *flag;
  for (int c = threadIdx.x; c < FD; c += 256) {
    float m = st[c] / Mf;
    float v = fmaxf(st[FD + c] / Mf - m * m, 0.f);
    float sc = ldf(gamma, goff + c, f) * rsqrtf(v + 1e-5f);
    scsh[c] = sc;
    scsh[FD + c] = ldf(beta, goff + c, f) - m * sc;
  }
  __syncthreads();
  int p = blockIdx.x * 256 + threadIdx.x;
  if (p >= total8) return;
  int e = p * 8;
  int col = e & (FD - 1);
  uint4 u = *(const uint4*)(x + e);
  bf162_t* pr = (bf162_t*)&u;
  uint4 ov;
  bf162_t* po = (bf162_t*)&ov;
#pragma unroll
  for (int i = 0; i < 4; ++i) {
    float x0 = __bfloat162float(pr[i].x) * scsh[col + 2 * i] + scsh[FD + col + 2 * i];
    float x1 = __bfloat162float(pr[i].y) * scsh[col + 2 * i + 1] + scsh[FD + col + 2 * i + 1];
    po[i].x = __float2bfloat16(fmaxf(0.f, x0));
    po[i].y = __float2bfloat16(fmaxf(0.f, x1));
  }
  *(uint4*)(out + e) = ov;
}

// ---------------- host orchestration ----------------
extern "C" void kernel_launch(void* const* d_in, const int* in_sizes, int n_in,
                              void* d_out, int out_size, void* d_ws, size_t ws_size,
                              hipStream_t stream) {
  const int Mn = in_sizes[0] / FD;          // 20000
  const int Mp = (Mn + 127) & ~127;         // 20096
  const int E = in_sizes[14];               // 320000
  const size_t SZ = (size_t)FD * FD;

  const void* hd_raw = d_in[0];
  const void* hp_raw = d_in[1];
  const void* Ws1 = d_in[2];
  const void* Wn1 = d_in[3];
  const void* b1 = d_in[4];
  const void* Ws2 = d_in[5];
  const void* Wn2 = d_in[6];
  const void* b2 = d_in[7];
  const void* bng = d_in[8];
  const void* bnb = d_in[9];
  const void* pWd = d_in[10];
  const void* pbd = d_in[11];
  const void* pWp = d_in[12];
  const void* pbp = d_in[13];
  const int* a_src = (const int*)d_in[14];
  const int* a_dst = (const int*)d_in[15];
  const int* i_src = (const int*)d_in[16];
  const int* i_dst = (const int*)d_in[17];

  char* wptr = (char*)d_ws;
  auto alloc = [&](size_t bytes) {
    char* p = wptr;
    wptr += (bytes + 255) & ~(size_t)255;
    return p;
  };
  bf16_t* Bt = (bf16_t*)alloc(14 * SZ * 2);
  float* biasf = (float*)alloc(6 * FD * 4);
  float* stats = (float*)alloc(8 * FD * 4);  // layer1: [sum_d|sq_d|sum_p|sq_p], layer2: +4FD
  int* dtflag = (int*)alloc(256);
  int* deg = (int*)alloc((size_t)4 * Mn * 4);
  int* offs = (int*)alloc((size_t)4 * (Mn + 1) * 4);
  int* curs = (int*)alloc((size_t)4 * Mn * 4);
  int* evals = (int*)alloc((size_t)4 * E * 4);
  bf16_t* accd = (bf16_t*)alloc((size_t)Mp * FD * 2);  // pre-BN disease (concurrent w/ accp)
  bf16_t* accp = (bf16_t*)alloc((size_t)Mp * FD * 2);  // pre-BN protein
  bf16_t* h_d = (bf16_t*)alloc((size_t)Mp * FD * 2);
  bf16_t* h_p = (bf16_t*)alloc((size_t)Mp * FD * 2);
  bf16_t* mean0 = (bf16_t*)alloc((size_t)Mp * FD * 2);
  bf16_t* mean1 = (bf16_t*)alloc((size_t)Mp * FD * 2);
  bf16_t* mean2 = (bf16_t*)alloc((size_t)Mp * FD * 2);
  bf16_t* mean3 = (bf16_t*)alloc((size_t)Mp * FD * 2);

  detect_k<<<1, 256, 0, stream>>>((const unsigned int*)hd_raw, 4096, dtflag);
  const int nh = Mn * FD, nhp = Mp * FD;
  conv_h_k<<<dim3((nhp / 4 + 255) / 256, 2), 256, 0, stream>>>(hd_raw, hp_raw, h_d, h_p, nh, nhp,
                                                               dtflag);

  hipMemsetAsync(deg, 0, (size_t)4 * Mn * 4, stream);
  hipMemsetAsync(stats, 0, 8 * FD * 4, stream);  // once, both layers (disjoint sections)
  int eb = (E + 255) / 256;
  count_deg_k<<<eb, 256, 0, stream>>>(a_src, a_dst, i_src, i_dst, deg, Mn, E);
  scan_k<<<4, 256, 0, stream>>>(deg, offs, curs, Mn);
  fill_k<<<dim3(eb, 4), 256, 0, stream>>>(a_src, a_dst, i_src, i_dst, curs, evals, Mn, E);

  // Bt slots: [0..3]=Wn1T[r], [4..7]=Wn2T[r], [8]=Ws1(0+2+3)T, [9]=Ws1(1)T,
  //           [10]=Ws2(0+2+3)T, [11]=Ws2(1)T, [12]=projWdT, [13]=projWpT
  TSlots ts;
  for (int z = 0; z < 14; ++z) { ts.s1[z] = -1; ts.s2[z] = -1; ts.o1[z] = 0; ts.o2[z] = 0; }
  for (int r = 0; r < 4; ++r) { ts.s0[r] = 1; ts.o0[r] = (unsigned long long)r * SZ; }
  for (int r = 0; r < 4; ++r) { ts.s0[4 + r] = 3; ts.o0[4 + r] = (unsigned long long)r * SZ; }
  ts.s0[8] = 0; ts.o0[8] = 0; ts.s1[8] = 0; ts.o1[8] = 2 * SZ; ts.s2[8] = 0; ts.o2[8] = 3 * SZ;
  ts.s0[9] = 0; ts.o0[9] = 1 * SZ;
  ts.s0[10] = 2; ts.o0[10] = 0; ts.s1[10] = 2; ts.o1[10] = 2 * SZ; ts.s2[10] = 2; ts.o2[10] = 3 * SZ;
  ts.s0[11] = 2; ts.o0[11] = 1 * SZ;
  ts.s0[12] = 4; ts.o0[12] = 0;
  ts.s0[13] = 5; ts.o0[13] = 0;
  transpose_all_k<<<dim3(16, 16, 14), dim3(32, 8), 0, stream>>>(Ws1, Wn1, Ws2, Wn2, pWd, pWp,
                                                                ts, Bt, dtflag);
  prep_bias_k<<<1, 256, 0, stream>>>(b1, b2, pbd, pbp, biasf, dtflag);

  dim3 ggrid(4, Mp / 128, 2);
  dim3 sgrid(Mp / 32, 32);  // x = node-group (32 nodes/block), y swizzled to (rel,slice)
  const int bn8 = (Mn * FD / 8 + 255) / 256;

  auto layer = [&](int wn0, int wsp, int wsd, const float* bd, const float* bp,
                   float* st, unsigned long long goff_d, unsigned long long goff_p) {
    seg_mean_g8_k<<<sgrid, 256, 0, stream>>>(h_d, h_p, offs, evals, Mn, E, mean0, mean1,
                                             mean2, mean3);
    // one dispatch: z=0 disease = hd@Ws[1] + mean1@Wn[1] (NSEG=2),
    //               z=1 protein = hp@(Ws0+2+3) + mean0@Wn0 + mean2@Wn2 + mean3@Wn3 (NSEG=4)
    gemm_layer_k<<<ggrid, 256, 0, stream>>>(
        h_d, mean1, Bt + (size_t)wsd * SZ, Bt + (size_t)(wn0 + 1) * SZ,
        h_p, mean0, mean2, mean3,
        Bt + (size_t)wsp * SZ, Bt + (size_t)(wn0 + 0) * SZ,
        Bt + (size_t)(wn0 + 2) * SZ, Bt + (size_t)(wn0 + 3) * SZ,
        bd, bp, accd, accp, st, Mn);
    bn2_apply_k<<<dim3(bn8, 2), 256, 0, stream>>>(accd, accp, st, bng, bnb, goff_d, goff_p,
                                                  (float)Mn, h_d, h_p, Mn * FD / 8, dtflag);
  };

  // bn params layout [layer][ntype][512], ntype 0=disease 1=protein
  layer(0, 8, 9, biasf + 0 * FD, biasf + 1 * FD, stats, 0ULL * FD, 1ULL * FD);
  layer(4, 10, 11, biasf + 2 * FD, biasf + 3 * FD, stats + 4 * FD, 2ULL * FD, 3ULL * FD);

  // merged final projections -> d_out (z=0: disease half, z=1: protein half)
  gemm_final_k<<<dim3(4, Mp / 128, 2), 256, 0, stream>>>(
      h_d, h_p, Bt + 12 * SZ, Bt + 13 * SZ, biasf + 4 * FD, d_out, Mn, dtflag);
}